// Round 9
// baseline (116.135 us; speedup 1.0000x reference)
//
#include <hip/hip_runtime.h>
#include <stdint.h>

typedef __bf16 bf16;
typedef __bf16 bf16x8 __attribute__((ext_vector_type(8)));
typedef float  f32x4  __attribute__((ext_vector_type(4)));
typedef unsigned short u16x4 __attribute__((ext_vector_type(4)));
typedef unsigned int   u32x4v __attribute__((ext_vector_type(4)));

#define SEQ   2048
#define DM    768
#define NH    12
#define HD    64
#define ATT_SCALE 0.125f
#define LOG2E 1.44269504f
#define LN_EPS 1e-5f

// async global->LDS, 16B per lane; LDS dest is wave-uniform base + lane*16
__device__ __forceinline__ void gload16(const void* g, void* l) {
  __builtin_amdgcn_global_load_lds((const __attribute__((address_space(1))) void*)g,
                                   (__attribute__((address_space(3))) void*)l,
                                   16, 0, 0);
}

// ---------------- prep: LN (blocks 0..4095) + weight transpose (4096..6399) -
__global__ __launch_bounds__(256) void prep_kernel(
    const float* __restrict__ x, const float* __restrict__ gamma,
    const float* __restrict__ beta, bf16* __restrict__ h,
    const float* __restrict__ Wq, const float* __restrict__ Wk,
    const float* __restrict__ Wv, const float* __restrict__ Wo,
    bf16* __restrict__ Wqkvt, bf16* __restrict__ Wot)
{
  __shared__ float smem[32*33];
  int bid = blockIdx.x, t = threadIdx.x;
  if (bid < 4096) {
    const float* xr = x + (size_t)bid*DM;
    float v0 = xr[t], v1 = xr[t+256], v2 = xr[t+512];
    float s = v0+v1+v2;
    float q = v0*v0+v1*v1+v2*v2;
    #pragma unroll
    for (int m=32;m>=1;m>>=1){ s += __shfl_xor(s,m,64); q += __shfl_xor(q,m,64); }
    float* rs = smem; float* rq = smem+8;
    int w = t>>6;
    if ((t&63)==0){ rs[w]=s; rq[w]=q; }
    __syncthreads();
    float S = rs[0]+rs[1]+rs[2]+rs[3];
    float Q = rq[0]+rq[1]+rq[2]+rq[3];
    float mean = S*(1.0f/DM);
    float var  = Q*(1.0f/DM) - mean*mean;
    float rstd = rsqrtf(var + LN_EPS);
    bf16* hr = h + (size_t)bid*DM;
    hr[t]     = (bf16)((v0-mean)*rstd*gamma[t]     + beta[t]);
    hr[t+256] = (bf16)((v1-mean)*rstd*gamma[t+256] + beta[t+256]);
    hr[t+512] = (bf16)((v2-mean)*rstd*gamma[t+512] + beta[t+512]);
  } else {
    int tb = bid - 4096;
    int z = tb/576, rem = tb%576;
    int r0 = (rem/24)*32, c0 = (rem%24)*32;
    int tx = t&31, ty = t>>5;   // (32,8)
    float (*tile)[33] = (float(*)[33])smem;
    const float* src = (z==0)?Wq:(z==1)?Wk:(z==2)?Wv:Wo;
    #pragma unroll
    for (int i=ty;i<32;i+=8) tile[i][tx] = src[(size_t)(r0+i)*DM + c0+tx];
    __syncthreads();
    bf16* dst = (z<3) ? (Wqkvt + (size_t)z*DM*DM) : Wot;
    #pragma unroll
    for (int i=ty;i<32;i+=8) dst[(size_t)(c0+i)*DM + r0+tx] = (bf16)tile[tx][i];
  }
}

// ---------------- GEMM: C = A * Bt^T, BK=32, 3-buffer counted-vmcnt pipeline -
// EPI 0: QKV epilogue (Q cols scaled LOG2E; V -> V^T [b][h][d][n])
// EPI 1: out fp32 = acc + bo[col] + x[row][col]
template<int BM, int BN, int WM, int WN, int EPI>
__global__ __launch_bounds__(256) void gemm_bt(
    const bf16* __restrict__ A, const bf16* __restrict__ Bt, int K,
    bf16* __restrict__ qk, bf16* __restrict__ vt,
    float* __restrict__ out, const float* __restrict__ bo, const float* __restrict__ xres)
{
  constexpr int MF = BM/(WM*16);
  constexpr int NF = BN/(WN*16);
  constexpr int GL = BM/64 + BN/64;   // gloads per wave per stage
  __shared__ bf16 As[3][BM][32];
  __shared__ bf16 Bs[3][BN][32];
  int tid = threadIdx.x, w = tid>>6, la = tid&63;
  int bn = blockIdx.x, bm = blockIdx.y;
  int wm = w / WN, wn = w % WN;
  int g = la>>4, li = la&15;
  int sr = la>>2, sc = (la&3)*8;      // staging: 4 lanes per 32-elem row
  f32x4 acc[MF][NF] = {};
  const int KT = K/32;

  auto stage = [&](int kt, int bb) {
    int k0 = kt*32;
    #pragma unroll
    for (int i=0;i<BM/64;i++){ int r0 = i*64 + w*16;
      gload16(A + ((size_t)(bm*BM + r0 + sr))*K + k0 + sc, &As[bb][r0][0]); }
    #pragma unroll
    for (int i=0;i<BN/64;i++){ int r0 = i*64 + w*16;
      gload16(Bt + ((size_t)(bn*BN + r0 + sr))*K + k0 + sc, &Bs[bb][r0][0]); }
  };

  stage(0,0); stage(1,1);
  asm volatile("s_waitcnt vmcnt(%0)" :: "n"(GL) : "memory");
  __builtin_amdgcn_s_barrier();
  __builtin_amdgcn_sched_barrier(0);

  for (int kt=0; kt<KT; ++kt) {
    int bb = kt%3;
    if (kt+2 < KT) stage(kt+2, (kt+2)%3);
    bf16x8 af[MF], bfr[NF];
    #pragma unroll
    for (int i=0;i<MF;i++) af[i]  = *(const bf16x8*)&As[bb][wm*(BM/WM)+i*16+li][g*8];
    #pragma unroll
    for (int j=0;j<NF;j++) bfr[j] = *(const bf16x8*)&Bs[bb][wn*(BN/WN)+j*16+li][g*8];
    __builtin_amdgcn_s_setprio(1);
    #pragma unroll
    for (int i=0;i<MF;i++)
      #pragma unroll
      for (int j=0;j<NF;j++)
        acc[i][j] = __builtin_amdgcn_mfma_f32_16x16x32_bf16(af[i], bfr[j], acc[i][j], 0,0,0);
    __builtin_amdgcn_s_setprio(0);
    if (kt+1 < KT) {
      if (kt+2 < KT) asm volatile("s_waitcnt vmcnt(%0)" :: "n"(GL) : "memory");
      else           asm volatile("s_waitcnt vmcnt(0)" ::: "memory");
      __builtin_amdgcn_s_barrier();
      __builtin_amdgcn_sched_barrier(0);
    }
  }

  #pragma unroll
  for (int i=0;i<MF;i++){
    int row0 = bm*BM + wm*(BM/WM) + i*16 + g*4;
    #pragma unroll
    for (int j=0;j<NF;j++){
      int col = bn*BN + wn*(BN/WN) + j*16 + li;
      if (EPI==0){
        if (col < 1536) {
          float qs = (col < 768) ? LOG2E : 1.0f;   // uniform per j-tile (768%BN==0)
          #pragma unroll
          for (int r=0;r<4;r++) qk[(size_t)(row0+r)*1536 + col] = (bf16)(acc[i][j][r]*qs);
        } else {
          int cv = col - 1536; int hh = cv>>6, dd = cv&63;
          int b_ = row0>>11,  n0 = row0&2047;
          u16x4 u;
          #pragma unroll
          for (int r=0;r<4;r++){ bf16 bv = (bf16)acc[i][j][r];
            u[r] = __builtin_bit_cast(unsigned short, bv); }
          *reinterpret_cast<u16x4*>(vt + ((size_t)((b_*NH+hh)*HD+dd))*SEQ + n0) = u;
        }
      } else {
        float bb2 = bo[col];
        #pragma unroll
        for (int r=0;r<4;r++){ size_t idx = (size_t)(row0+r)*DM + col;
          out[idx] = acc[i][j][r] + bb2 + xres[idx]; }
      }
    }
  }
}

// ---------------- flash attention, KV-split: 32q/wave AND 12 waves/CU -------
// Static-max softmax is exactly additive across KV ranges, so each (b,h,qt)
// tile is computed by TWO blocks (one per KV half): grid 1536 restores
// 12 waves/CU (round-7 occupancy) while keeping 32q/wave (round-8 LDS
// amortization). Raw partial O (bf16, no 1/l) -> d_out (dead until GEMM2;
// 2 x 6.29MB fills its 12.58MB exactly); partial l -> dead Wqkvt region.
// 2-buffer LDS (32KB): {stage(t+1); compute(t); vmcnt(0); barrier} is
// race-free (stage(t+2) starts only after all readers passed the barrier).
__global__ __launch_bounds__(128) void attn_kernel(
    const bf16* __restrict__ QK, const bf16* __restrict__ Vt,
    bf16* __restrict__ Opart, float* __restrict__ lpart)
{
  __shared__ bf16 Ks[2][64][64];
  __shared__ bf16 Vs[2][64][64];   // V^T tile: [d][kv]
  int tid=threadIdx.x, w=tid>>6, la=tid&63;
  int id = blockIdx.x;
  int xcd = id & 7, idx = id >> 3;       // 1536 = 8 * 192, bijective
  int bh  = xcd*3 + idx/64;              // 3 (b,h) per XCD -> K/V L2-resident
  int rem = idx & 63;
  int qt  = rem >> 1;                    // 0..31
  int kvh = rem & 1;                     // KV half
  int b = bh/NH, hh = bh%NH;
  int g=la>>4, li=la&15;
  int lr=la>>3;
  int lx=li&7;
  int lcs=((la&7)^lr)*8;           // swizzled source column (elements)
  size_t qrow0=(size_t)b*SEQ + qt*64;
  int kv0 = kvh*1024;

  // Q frags (B-operand: Q[q][k]) for two q-tiles, pre-scaled by LOG2E
  bf16x8 qf[2][2];   // [kk][qh]
  #pragma unroll
  for (int qh=0;qh<2;qh++){
    const bf16* qp = QK + (qrow0 + w*32 + qh*16 + li)*1536 + hh*64;
    qf[0][qh] = *(const bf16x8*)(qp + g*8);
    qf[1][qh] = *(const bf16x8*)(qp + 32 + g*8);
  }

  // all-ones A-frag for the l-sum MFMA
  bf16x8 onef;
  {
    unsigned int one2 = 0x3F803F80u;   // {1.0bf16, 1.0bf16}
    u32x4v oc = {one2, one2, one2, one2};
    onef = __builtin_bit_cast(bf16x8, oc);
  }

  const bf16* Kbase = QK + (size_t)b*SEQ*1536 + 768 + hh*64;
  const bf16* Vbase = Vt + (size_t)(b*NH+hh)*HD*SEQ;

  auto stage = [&](int tt, int bb) {
    int j0 = kv0 + tt*64;
    #pragma unroll
    for (int i=0;i<4;i++){ int c=i*2+w;
      gload16(Kbase + (size_t)(j0 + c*8 + lr)*1536 + lcs, &Ks[bb][c*8][0]);
      gload16(Vbase + (size_t)(c*8 + lr)*SEQ + j0 + lcs,  &Vs[bb][c*8][0]); }
  };

  stage(0,0);
  asm volatile("s_waitcnt vmcnt(0)" ::: "memory");
  __builtin_amdgcn_s_barrier();
  __builtin_amdgcn_sched_barrier(0);

  f32x4 o[2][4] = {};      // [qh][df]
  f32x4 ol[2] = {};        // [qh] l-sum rows (all r identical)

  for (int t=0;t<16;t++){
    int bb = t&1;
    if (t+1 < 16) stage(t+1, bb^1);
    // S = K Q^T (swapped): lane holds S[kv=nf*16+g*4+r][q=li] per q-tile
    f32x4 s[2][4] = {};
    #pragma unroll
    for (int kk=0;kk<2;kk++){
      bf16x8 kf[4];
      #pragma unroll
      for (int nf=0;nf<4;nf++){
        int row = nf*16+li;
        kf[nf] = *(const bf16x8*)((const char*)&Ks[bb][0][0] + row*128 + (((kk*4+g)^lx)<<4));
      }
      __builtin_amdgcn_s_setprio(1);
      #pragma unroll
      for (int nf=0;nf<4;nf++){
        s[0][nf] = __builtin_amdgcn_mfma_f32_16x16x32_bf16(kf[nf], qf[kk][0], s[0][nf], 0,0,0);
        s[1][nf] = __builtin_amdgcn_mfma_f32_16x16x32_bf16(kf[nf], qf[kk][1], s[1][nf], 0,0,0);
      }
      __builtin_amdgcn_s_setprio(0);
    }
    // static-max softmax + in-register exchange, per q-tile
    bf16x8 pa[2][2];   // [qh][ks]
    #pragma unroll
    for (int qh=0;qh<2;qh++){
      float p[4][4];
      #pragma unroll
      for (int nf=0;nf<4;nf++)
        #pragma unroll
        for (int r=0;r<4;r++)
          p[nf][r] = __builtin_amdgcn_exp2f(s[qh][nf][r]);
      #pragma unroll
      for (int ks=0;ks<2;ks++){
        unsigned int c00,c01,c10,c11;
        asm("v_cvt_pk_bf16_f32 %0, %1, %2" : "=v"(c00) : "v"(p[2*ks  ][0]), "v"(p[2*ks  ][1]));
        asm("v_cvt_pk_bf16_f32 %0, %1, %2" : "=v"(c01) : "v"(p[2*ks  ][2]), "v"(p[2*ks  ][3]));
        asm("v_cvt_pk_bf16_f32 %0, %1, %2" : "=v"(c10) : "v"(p[2*ks+1][0]), "v"(p[2*ks+1][1]));
        asm("v_cvt_pk_bf16_f32 %0, %1, %2" : "=v"(c11) : "v"(p[2*ks+1][2]), "v"(p[2*ks+1][3]));
        // transpose (reg-bit, lane-b5) then (reg-bit, lane-b4); reg0 word = vdst
        asm("v_permlane32_swap_b32 %0, %1" : "+v"(c00), "+v"(c10));
        asm("v_permlane32_swap_b32 %0, %1" : "+v"(c01), "+v"(c11));
        asm("v_permlane16_swap_b32 %0, %1" : "+v"(c00), "+v"(c10));
        asm("v_permlane16_swap_b32 %0, %1" : "+v"(c01), "+v"(c11));
        u32x4v cc = {c00, c01, c10, c11};
        pa[qh][ks] = __builtin_bit_cast(bf16x8, cc);
      }
    }
    // PV + l-sum: O[d][q] += V^T[d][kv] P[kv][q];  ol[q] += 1^T P[kv][q]
    #pragma unroll
    for (int ks=0;ks<2;ks++){
      bf16x8 vb[4];
      #pragma unroll
      for (int df=0;df<4;df++){
        int row = df*16+li;
        vb[df] = *(const bf16x8*)((const char*)&Vs[bb][0][0] + row*128 + (((ks*4+g)^lx)<<4));
      }
      __builtin_amdgcn_s_setprio(1);
      #pragma unroll
      for (int qh=0;qh<2;qh++){
        #pragma unroll
        for (int df=0;df<4;df++)
          o[qh][df] = __builtin_amdgcn_mfma_f32_16x16x32_bf16(vb[df], pa[qh][ks], o[qh][df], 0,0,0);
        ol[qh] = __builtin_amdgcn_mfma_f32_16x16x32_bf16(onef, pa[qh][ks], ol[qh], 0,0,0);
      }
      __builtin_amdgcn_s_setprio(0);
    }
    if (t+1 < 16) {
      asm volatile("s_waitcnt vmcnt(0)" ::: "memory");
      __builtin_amdgcn_s_barrier();
      __builtin_amdgcn_sched_barrier(0);
    }
  }
  // write raw partials. lane holds O[d=df*16+g*4+r][q=li]
  bf16* ob = Opart + (size_t)kvh*4096*DM;
  #pragma unroll
  for (int qh=0;qh<2;qh++){
    size_t row = qrow0 + w*32 + qh*16 + li;
    #pragma unroll
    for (int df=0;df<4;df++){
      u16x4 u;
      #pragma unroll
      for (int r=0;r<4;r++){
        bf16 bv = (bf16)o[qh][df][r];
        u[r] = __builtin_bit_cast(unsigned short, bv);
      }
      *reinterpret_cast<u16x4*>(ob + row*DM + hh*64 + df*16 + g*4) = u;
    }
    if (g==0) lpart[(size_t)kvh*24*SEQ + (size_t)bh*SEQ + qt*64 + w*32 + qh*16 + li] = ol[qh][0];
  }
}

// ---------------- reduce: vals = (O_a + O_b) * SCALE / (l_a + l_b) ----------
__global__ __launch_bounds__(256) void reduce_kernel(
    const bf16* __restrict__ Op, const float* __restrict__ lp, bf16* __restrict__ vals)
{
  int gid = blockIdx.x*256 + threadIdx.x;   // 0..393215 (4096 rows x 96 vec8)
  int r = gid/96, cv = gid - r*96;
  int c0 = cv*8;
  int b = r>>11, q = r&2047, h = c0>>6;
  size_t li = (size_t)(b*NH + h)*SEQ + q;
  float l = lp[li] + lp[(size_t)24*SEQ + li];
  float fac = ATT_SCALE / l;
  bf16x8 a = *(const bf16x8*)(Op + (size_t)r*DM + c0);
  bf16x8 bb = *(const bf16x8*)(Op + (size_t)4096*DM + (size_t)r*DM + c0);
  bf16x8 o;
  #pragma unroll
  for (int i=0;i<8;i++) o[i] = (bf16)(((float)a[i] + (float)bb[i]) * fac);
  *(bf16x8*)(vals + (size_t)r*DM + c0) = o;
}

// ---------------- launch -----------------------------------------------------
extern "C" void kernel_launch(void* const* d_in, const int* in_sizes, int n_in,
                              void* d_out, int out_size, void* d_ws, size_t ws_size,
                              hipStream_t stream)
{
  const float* x     = (const float*)d_in[0];
  const float* Wq    = (const float*)d_in[1];
  const float* Wk    = (const float*)d_in[2];
  const float* Wv    = (const float*)d_in[3];
  const float* Wo    = (const float*)d_in[4];
  const float* bo    = (const float*)d_in[5];
  const float* gamma = (const float*)d_in[6];
  const float* beta  = (const float*)d_in[7];
  float* out = (float*)d_out;
  char* ws = (char*)d_ws;

  bf16* h     = (bf16*)(ws + 0);          // 4096*768*2    = 6291456
  bf16* vals  = (bf16*)(ws + 0);          // alias of h (h dead after GEMM1)
  bf16* Wqkvt = (bf16*)(ws + 6291456);    // 2304*768*2    = 3538944
  bf16* Wot   = (bf16*)(ws + 9830400);    // 768*768*2     = 1179648
  bf16* QKb   = (bf16*)(ws + 11010048);   // 4096*1536*2   = 12582912
  bf16* Vt    = (bf16*)(ws + 23592960);   // 24*64*2048*2  = 6291456
  // partials: Opart -> d_out (2 x bf16 [4096][768] = exactly its 12.58MB,
  // dead until GEMM2 overwrites); lpart -> dead Wqkvt region (393KB,
  // Wqkvt is only read by GEMM1 which completes before attn).
  bf16*  Opart = (bf16*)d_out;
  float* lpart = (float*)(ws + 6291456);
  (void)ws_size; (void)in_sizes; (void)n_in; (void)out_size;

  prep_kernel<<<dim3(6400), dim3(256), 0, stream>>>(
      x, gamma, beta, h, Wq, Wk, Wv, Wo, Wqkvt, Wot);
  gemm_bt<128,128,2,2,0><<<dim3(18,32), dim3(256), 0, stream>>>(
      h, Wqkvt, DM, QKb, Vt, nullptr, nullptr, nullptr);
  attn_kernel<<<dim3(1536), dim3(128), 0, stream>>>(QKb, Vt, Opart, lpart);
  reduce_kernel<<<dim3(1536), dim3(256), 0, stream>>>(Opart, lpart, vals);
  gemm_bt<64,64,2,2,1><<<dim3(12,64), dim3(256), 0, stream>>>(
      vals, Wot, DM, nullptr, nullptr, out, bo, x);
}

// Round 10
// 110.759 us; speedup vs baseline: 1.0485x; 1.0485x over previous
//
#include <hip/hip_runtime.h>
#include <stdint.h>

typedef __bf16 bf16;
typedef __bf16 bf16x8 __attribute__((ext_vector_type(8)));
typedef float  f32x4  __attribute__((ext_vector_type(4)));
typedef unsigned short u16x4 __attribute__((ext_vector_type(4)));
typedef unsigned int   u32x4v __attribute__((ext_vector_type(4)));

#define SEQ   2048
#define DM    768
#define NH    12
#define HD    64
#define ATT_SCALE 0.125f
#define LOG2E 1.44269504f
#define LN_EPS 1e-5f

// async global->LDS, 16B per lane; LDS dest is wave-uniform base + lane*16
__device__ __forceinline__ void gload16(const void* g, void* l) {
  __builtin_amdgcn_global_load_lds((const __attribute__((address_space(1))) void*)g,
                                   (__attribute__((address_space(3))) void*)l,
                                   16, 0, 0);
}

// ---------------- prep: LN (blocks 0..4095) + weight transpose (4096..6399) -
__global__ __launch_bounds__(256) void prep_kernel(
    const float* __restrict__ x, const float* __restrict__ gamma,
    const float* __restrict__ beta, bf16* __restrict__ h,
    const float* __restrict__ Wq, const float* __restrict__ Wk,
    const float* __restrict__ Wv, const float* __restrict__ Wo,
    bf16* __restrict__ Wqkvt, bf16* __restrict__ Wot)
{
  __shared__ float smem[32*33];
  int bid = blockIdx.x, t = threadIdx.x;
  if (bid < 4096) {
    const float* xr = x + (size_t)bid*DM;
    float v0 = xr[t], v1 = xr[t+256], v2 = xr[t+512];
    float s = v0+v1+v2;
    float q = v0*v0+v1*v1+v2*v2;
    #pragma unroll
    for (int m=32;m>=1;m>>=1){ s += __shfl_xor(s,m,64); q += __shfl_xor(q,m,64); }
    float* rs = smem; float* rq = smem+8;
    int w = t>>6;
    if ((t&63)==0){ rs[w]=s; rq[w]=q; }
    __syncthreads();
    float S = rs[0]+rs[1]+rs[2]+rs[3];
    float Q = rq[0]+rq[1]+rq[2]+rq[3];
    float mean = S*(1.0f/DM);
    float var  = Q*(1.0f/DM) - mean*mean;
    float rstd = rsqrtf(var + LN_EPS);
    bf16* hr = h + (size_t)bid*DM;
    hr[t]     = (bf16)((v0-mean)*rstd*gamma[t]     + beta[t]);
    hr[t+256] = (bf16)((v1-mean)*rstd*gamma[t+256] + beta[t+256]);
    hr[t+512] = (bf16)((v2-mean)*rstd*gamma[t+512] + beta[t+512]);
  } else {
    int tb = bid - 4096;
    int z = tb/576, rem = tb%576;
    int r0 = (rem/24)*32, c0 = (rem%24)*32;
    int tx = t&31, ty = t>>5;   // (32,8)
    float (*tile)[33] = (float(*)[33])smem;
    const float* src = (z==0)?Wq:(z==1)?Wk:(z==2)?Wv:Wo;
    #pragma unroll
    for (int i=ty;i<32;i+=8) tile[i][tx] = src[(size_t)(r0+i)*DM + c0+tx];
    __syncthreads();
    bf16* dst = (z<3) ? (Wqkvt + (size_t)z*DM*DM) : Wot;
    #pragma unroll
    for (int i=ty;i<32;i+=8) dst[(size_t)(c0+i)*DM + r0+tx] = (bf16)tile[tx][i];
  }
}

// ---------------- GEMM: C = A * Bt^T, BK=32, 3-buffer counted-vmcnt pipeline -
// EPI 0: QKV epilogue (Q cols scaled LOG2E; V -> V^T [b][h][d][n])
// EPI 1: out fp32 = acc + bo[col] + x[row][col]
template<int BM, int BN, int WM, int WN, int EPI>
__global__ __launch_bounds__(256) void gemm_bt(
    const bf16* __restrict__ A, const bf16* __restrict__ Bt, int K,
    bf16* __restrict__ qk, bf16* __restrict__ vt,
    float* __restrict__ out, const float* __restrict__ bo, const float* __restrict__ xres)
{
  constexpr int MF = BM/(WM*16);
  constexpr int NF = BN/(WN*16);
  constexpr int GL = BM/64 + BN/64;   // gloads per wave per stage
  __shared__ bf16 As[3][BM][32];
  __shared__ bf16 Bs[3][BN][32];
  int tid = threadIdx.x, w = tid>>6, la = tid&63;
  int bn = blockIdx.x, bm = blockIdx.y;
  int wm = w / WN, wn = w % WN;
  int g = la>>4, li = la&15;
  int sr = la>>2, sc = (la&3)*8;      // staging: 4 lanes per 32-elem row
  f32x4 acc[MF][NF] = {};
  const int KT = K/32;

  auto stage = [&](int kt, int bb) {
    int k0 = kt*32;
    #pragma unroll
    for (int i=0;i<BM/64;i++){ int r0 = i*64 + w*16;
      gload16(A + ((size_t)(bm*BM + r0 + sr))*K + k0 + sc, &As[bb][r0][0]); }
    #pragma unroll
    for (int i=0;i<BN/64;i++){ int r0 = i*64 + w*16;
      gload16(Bt + ((size_t)(bn*BN + r0 + sr))*K + k0 + sc, &Bs[bb][r0][0]); }
  };

  stage(0,0); stage(1,1);
  asm volatile("s_waitcnt vmcnt(%0)" :: "n"(GL) : "memory");
  __builtin_amdgcn_s_barrier();
  __builtin_amdgcn_sched_barrier(0);

  for (int kt=0; kt<KT; ++kt) {
    int bb = kt%3;
    if (kt+2 < KT) stage(kt+2, (kt+2)%3);
    bf16x8 af[MF], bfr[NF];
    #pragma unroll
    for (int i=0;i<MF;i++) af[i]  = *(const bf16x8*)&As[bb][wm*(BM/WM)+i*16+li][g*8];
    #pragma unroll
    for (int j=0;j<NF;j++) bfr[j] = *(const bf16x8*)&Bs[bb][wn*(BN/WN)+j*16+li][g*8];
    __builtin_amdgcn_s_setprio(1);
    #pragma unroll
    for (int i=0;i<MF;i++)
      #pragma unroll
      for (int j=0;j<NF;j++)
        acc[i][j] = __builtin_amdgcn_mfma_f32_16x16x32_bf16(af[i], bfr[j], acc[i][j], 0,0,0);
    __builtin_amdgcn_s_setprio(0);
    if (kt+1 < KT) {
      if (kt+2 < KT) asm volatile("s_waitcnt vmcnt(%0)" :: "n"(GL) : "memory");
      else           asm volatile("s_waitcnt vmcnt(0)" ::: "memory");
      __builtin_amdgcn_s_barrier();
      __builtin_amdgcn_sched_barrier(0);
    }
  }

  #pragma unroll
  for (int i=0;i<MF;i++){
    int row0 = bm*BM + wm*(BM/WM) + i*16 + g*4;
    #pragma unroll
    for (int j=0;j<NF;j++){
      int col = bn*BN + wn*(BN/WN) + j*16 + li;
      if (EPI==0){
        if (col < 1536) {
          float qs = (col < 768) ? LOG2E : 1.0f;   // uniform per j-tile (768%BN==0)
          #pragma unroll
          for (int r=0;r<4;r++) qk[(size_t)(row0+r)*1536 + col] = (bf16)(acc[i][j][r]*qs);
        } else {
          int cv = col - 1536; int hh = cv>>6, dd = cv&63;
          int b_ = row0>>11,  n0 = row0&2047;
          u16x4 u;
          #pragma unroll
          for (int r=0;r<4;r++){ bf16 bv = (bf16)acc[i][j][r];
            u[r] = __builtin_bit_cast(unsigned short, bv); }
          *reinterpret_cast<u16x4*>(vt + ((size_t)((b_*NH+hh)*HD+dd))*SEQ + n0) = u;
        }
      } else {
        float bb2 = bo[col];
        #pragma unroll
        for (int r=0;r<4;r++){ size_t idx = (size_t)(row0+r)*DM + col;
          out[idx] = acc[i][j][r] + bb2 + xres[idx]; }
      }
    }
  }
}

// ---------------- flash attention: 4 waves x 32q + KV-split + counted vmcnt -
// 256-thread blocks (empirical: HW co-schedules ~2 blocks/CU regardless of
// size, so 4-wave blocks -> 8 waves/CU; round 8/9's 2-wave blocks wasted half
// the SIMDs). Each wave owns 32 q-rows: the 16 ds_read_b128/iter serve 2048
// scores (2x round 7's amortization). KV-split x2 (exactly additive under
// static-max): grid = 24bh x 16qt(128q) x 2kvh = 768, XCD-pinned. 3-buffer
// LDS (48KB), counted vmcnt(4) (=GL) per barrier, never 0 mid-loop.
// Partial O (bf16, no 1/l) -> d_out (dead until GEMM2); partial l -> ws.
__global__ __launch_bounds__(256) void attn_kernel(
    const bf16* __restrict__ QK, const bf16* __restrict__ Vt,
    bf16* __restrict__ Opart, float* __restrict__ lpart)
{
  __shared__ bf16 Ks[3][64][64];
  __shared__ bf16 Vs[3][64][64];   // V^T tile: [d][kv]
  int tid=threadIdx.x, w=tid>>6, la=tid&63;
  int id = blockIdx.x;
  int xcd = id & 7, idx = id >> 3;       // 768 = 8 * 96, bijective
  int bh  = xcd*3 + idx/32;              // 3 (b,h) per XCD -> K/V L2-resident
  int rem = idx & 31;
  int qt  = rem >> 1;                    // 0..15 (128-q tiles)
  int kvh = rem & 1;                     // KV half
  int b = bh/NH, hh = bh%NH;
  int g=la>>4, li=la&15;
  int lr=la>>3;
  int lx=li&7;
  int lcs=((la&7)^lr)*8;           // swizzled source column (elements)
  size_t qrow0=(size_t)b*SEQ + qt*128;
  int kv0 = kvh*1024;

  // Q frags (B-operand: Q[q][k]) for two q-tiles, pre-scaled by LOG2E
  bf16x8 qf[2][2];   // [kk][qh]
  #pragma unroll
  for (int qh=0;qh<2;qh++){
    const bf16* qp = QK + (qrow0 + w*32 + qh*16 + li)*1536 + hh*64;
    qf[0][qh] = *(const bf16x8*)(qp + g*8);
    qf[1][qh] = *(const bf16x8*)(qp + 32 + g*8);
  }

  // all-ones A-frag for the l-sum MFMA
  bf16x8 onef;
  {
    unsigned int one2 = 0x3F803F80u;   // {1.0bf16, 1.0bf16}
    u32x4v oc = {one2, one2, one2, one2};
    onef = __builtin_bit_cast(bf16x8, oc);
  }

  const bf16* Kbase = QK + (size_t)b*SEQ*1536 + 768 + hh*64;
  const bf16* Vbase = Vt + (size_t)(b*NH+hh)*HD*SEQ;

  // 4 waves stage 8 row-groups: wave w does groups {w, 4+w} for K and V -> GL=4
  auto stage = [&](int tt, int bb) {
    int j0 = kv0 + tt*64;
    #pragma unroll
    for (int i=0;i<2;i++){ int c=i*4+w;
      gload16(Kbase + (size_t)(j0 + c*8 + lr)*1536 + lcs, &Ks[bb][c*8][0]);
      gload16(Vbase + (size_t)(c*8 + lr)*SEQ + j0 + lcs,  &Vs[bb][c*8][0]); }
  };

  stage(0,0); stage(1,1);
  asm volatile("s_waitcnt vmcnt(4)" ::: "memory");
  __builtin_amdgcn_s_barrier();
  __builtin_amdgcn_sched_barrier(0);

  f32x4 o[2][4] = {};      // [qh][df]
  f32x4 ol[2] = {};        // [qh] l-sum rows (all r identical)

  for (int t=0;t<16;t++){
    int bb = t%3;
    if (t+2 < 16) stage(t+2, (t+2)%3);
    // S = K Q^T (swapped): lane holds S[kv=nf*16+g*4+r][q=li] per q-tile
    f32x4 s[2][4] = {};
    #pragma unroll
    for (int kk=0;kk<2;kk++){
      bf16x8 kf[4];
      #pragma unroll
      for (int nf=0;nf<4;nf++){
        int row = nf*16+li;
        kf[nf] = *(const bf16x8*)((const char*)&Ks[bb][0][0] + row*128 + (((kk*4+g)^lx)<<4));
      }
      __builtin_amdgcn_s_setprio(1);
      #pragma unroll
      for (int nf=0;nf<4;nf++){
        s[0][nf] = __builtin_amdgcn_mfma_f32_16x16x32_bf16(kf[nf], qf[kk][0], s[0][nf], 0,0,0);
        s[1][nf] = __builtin_amdgcn_mfma_f32_16x16x32_bf16(kf[nf], qf[kk][1], s[1][nf], 0,0,0);
      }
      __builtin_amdgcn_s_setprio(0);
    }
    // static-max softmax + in-register exchange, per q-tile
    bf16x8 pa[2][2];   // [qh][ks]
    #pragma unroll
    for (int qh=0;qh<2;qh++){
      float p[4][4];
      #pragma unroll
      for (int nf=0;nf<4;nf++)
        #pragma unroll
        for (int r=0;r<4;r++)
          p[nf][r] = __builtin_amdgcn_exp2f(s[qh][nf][r]);
      #pragma unroll
      for (int ks=0;ks<2;ks++){
        unsigned int c00,c01,c10,c11;
        asm("v_cvt_pk_bf16_f32 %0, %1, %2" : "=v"(c00) : "v"(p[2*ks  ][0]), "v"(p[2*ks  ][1]));
        asm("v_cvt_pk_bf16_f32 %0, %1, %2" : "=v"(c01) : "v"(p[2*ks  ][2]), "v"(p[2*ks  ][3]));
        asm("v_cvt_pk_bf16_f32 %0, %1, %2" : "=v"(c10) : "v"(p[2*ks+1][0]), "v"(p[2*ks+1][1]));
        asm("v_cvt_pk_bf16_f32 %0, %1, %2" : "=v"(c11) : "v"(p[2*ks+1][2]), "v"(p[2*ks+1][3]));
        // transpose (reg-bit, lane-b5) then (reg-bit, lane-b4); reg0 word = vdst
        asm("v_permlane32_swap_b32 %0, %1" : "+v"(c00), "+v"(c10));
        asm("v_permlane32_swap_b32 %0, %1" : "+v"(c01), "+v"(c11));
        asm("v_permlane16_swap_b32 %0, %1" : "+v"(c00), "+v"(c10));
        asm("v_permlane16_swap_b32 %0, %1" : "+v"(c01), "+v"(c11));
        u32x4v cc = {c00, c01, c10, c11};
        pa[qh][ks] = __builtin_bit_cast(bf16x8, cc);
      }
    }
    // PV + l-sum: O[d][q] += V^T[d][kv] P[kv][q];  ol[q] += 1^T P[kv][q]
    #pragma unroll
    for (int ks=0;ks<2;ks++){
      bf16x8 vb[4];
      #pragma unroll
      for (int df=0;df<4;df++){
        int row = df*16+li;
        vb[df] = *(const bf16x8*)((const char*)&Vs[bb][0][0] + row*128 + (((ks*4+g)^lx)<<4));
      }
      __builtin_amdgcn_s_setprio(1);
      #pragma unroll
      for (int qh=0;qh<2;qh++){
        #pragma unroll
        for (int df=0;df<4;df++)
          o[qh][df] = __builtin_amdgcn_mfma_f32_16x16x32_bf16(vb[df], pa[qh][ks], o[qh][df], 0,0,0);
        ol[qh] = __builtin_amdgcn_mfma_f32_16x16x32_bf16(onef, pa[qh][ks], ol[qh], 0,0,0);
      }
      __builtin_amdgcn_s_setprio(0);
    }
    if (t+1 < 16) {
      if (t+2 < 16) asm volatile("s_waitcnt vmcnt(4)" ::: "memory");
      else          asm volatile("s_waitcnt vmcnt(0)" ::: "memory");
      __builtin_amdgcn_s_barrier();
      __builtin_amdgcn_sched_barrier(0);
    }
  }
  // write raw partials. lane holds O[d=df*16+g*4+r][q=li]
  bf16* ob = Opart + (size_t)kvh*4096*DM;
  #pragma unroll
  for (int qh=0;qh<2;qh++){
    size_t row = qrow0 + w*32 + qh*16 + li;
    #pragma unroll
    for (int df=0;df<4;df++){
      u16x4 u;
      #pragma unroll
      for (int r=0;r<4;r++){
        bf16 bv = (bf16)o[qh][df][r];
        u[r] = __builtin_bit_cast(unsigned short, bv);
      }
      *reinterpret_cast<u16x4*>(ob + row*DM + hh*64 + df*16 + g*4) = u;
    }
    if (g==0) lpart[(size_t)kvh*24*SEQ + (size_t)bh*SEQ + qt*128 + w*32 + qh*16 + li] = ol[qh][0];
  }
}

// ---------------- reduce: vals = (O_a + O_b) * SCALE / (l_a + l_b) ----------
__global__ __launch_bounds__(256) void reduce_kernel(
    const bf16* __restrict__ Op, const float* __restrict__ lp, bf16* __restrict__ vals)
{
  int gid = blockIdx.x*256 + threadIdx.x;   // 0..393215 (4096 rows x 96 vec8)
  int r = gid/96, cv = gid - r*96;
  int c0 = cv*8;
  int b = r>>11, q = r&2047, h = c0>>6;
  size_t li = (size_t)(b*NH + h)*SEQ + q;
  float l = lp[li] + lp[(size_t)24*SEQ + li];
  float fac = ATT_SCALE / l;
  bf16x8 a = *(const bf16x8*)(Op + (size_t)r*DM + c0);
  bf16x8 bb = *(const bf16x8*)(Op + (size_t)4096*DM + (size_t)r*DM + c0);
  bf16x8 o;
  #pragma unroll
  for (int i=0;i<8;i++) o[i] = (bf16)(((float)a[i] + (float)bb[i]) * fac);
  *(bf16x8*)(vals + (size_t)r*DM + c0) = o;
}

// ---------------- launch -----------------------------------------------------
extern "C" void kernel_launch(void* const* d_in, const int* in_sizes, int n_in,
                              void* d_out, int out_size, void* d_ws, size_t ws_size,
                              hipStream_t stream)
{
  const float* x     = (const float*)d_in[0];
  const float* Wq    = (const float*)d_in[1];
  const float* Wk    = (const float*)d_in[2];
  const float* Wv    = (const float*)d_in[3];
  const float* Wo    = (const float*)d_in[4];
  const float* bo    = (const float*)d_in[5];
  const float* gamma = (const float*)d_in[6];
  const float* beta  = (const float*)d_in[7];
  float* out = (float*)d_out;
  char* ws = (char*)d_ws;

  bf16* h     = (bf16*)(ws + 0);          // 4096*768*2    = 6291456
  bf16* vals  = (bf16*)(ws + 0);          // alias of h (h dead after GEMM1)
  bf16* Wqkvt = (bf16*)(ws + 6291456);    // 2304*768*2    = 3538944
  bf16* Wot   = (bf16*)(ws + 9830400);    // 768*768*2     = 1179648
  bf16* QKb   = (bf16*)(ws + 11010048);   // 4096*1536*2   = 12582912
  bf16* Vt    = (bf16*)(ws + 23592960);   // 24*64*2048*2  = 6291456
  // partials: Opart -> d_out (2 x bf16 [4096][768] = exactly its 12.58MB,
  // dead until GEMM2 overwrites); lpart -> dead Wqkvt region (393KB,
  // Wqkvt only read by GEMM1 which completes before attn).
  bf16*  Opart = (bf16*)d_out;
  float* lpart = (float*)(ws + 6291456);
  (void)ws_size; (void)in_sizes; (void)n_in; (void)out_size;

  prep_kernel<<<dim3(6400), dim3(256), 0, stream>>>(
      x, gamma, beta, h, Wq, Wk, Wv, Wo, Wqkvt, Wot);
  gemm_bt<128,128,2,2,0><<<dim3(18,32), dim3(256), 0, stream>>>(
      h, Wqkvt, DM, QKb, Vt, nullptr, nullptr, nullptr);
  attn_kernel<<<dim3(768), dim3(256), 0, stream>>>(QKb, Vt, Opart, lpart);
  reduce_kernel<<<dim3(1536), dim3(256), 0, stream>>>(Opart, lpart, vals);
  gemm_bt<64,64,2,2,1><<<dim3(12,64), dim3(256), 0, stream>>>(
      vals, Wot, DM, nullptr, nullptr, out, bo, x);
}

// Round 11
// 107.215 us; speedup vs baseline: 1.0832x; 1.0331x over previous
//
#include <hip/hip_runtime.h>
#include <stdint.h>

typedef __bf16 bf16;
typedef __bf16 bf16x8 __attribute__((ext_vector_type(8)));
typedef float  f32x4  __attribute__((ext_vector_type(4)));
typedef unsigned short u16x4 __attribute__((ext_vector_type(4)));
typedef unsigned int   u32x4v __attribute__((ext_vector_type(4)));

#define SEQ   2048
#define DM    768
#define NH    12
#define HD    64
#define ATT_SCALE 0.125f
#define LOG2E 1.44269504f
#define LN_EPS 1e-5f

// async global->LDS, 16B per lane; LDS dest is wave-uniform base + lane*16
__device__ __forceinline__ void gload16(const void* g, void* l) {
  __builtin_amdgcn_global_load_lds((const __attribute__((address_space(1))) void*)g,
                                   (__attribute__((address_space(3))) void*)l,
                                   16, 0, 0);
}

// ---------------- prep: LN (blocks 0..4095) + weight transpose (4096..6399) -
__global__ __launch_bounds__(256) void prep_kernel(
    const float* __restrict__ x, const float* __restrict__ gamma,
    const float* __restrict__ beta, bf16* __restrict__ h,
    const float* __restrict__ Wq, const float* __restrict__ Wk,
    const float* __restrict__ Wv, const float* __restrict__ Wo,
    bf16* __restrict__ Wqkvt, bf16* __restrict__ Wot)
{
  __shared__ float smem[32*33];
  int bid = blockIdx.x, t = threadIdx.x;
  if (bid < 4096) {
    const float* xr = x + (size_t)bid*DM;
    float v0 = xr[t], v1 = xr[t+256], v2 = xr[t+512];
    float s = v0+v1+v2;
    float q = v0*v0+v1*v1+v2*v2;
    #pragma unroll
    for (int m=32;m>=1;m>>=1){ s += __shfl_xor(s,m,64); q += __shfl_xor(q,m,64); }
    float* rs = smem; float* rq = smem+8;
    int w = t>>6;
    if ((t&63)==0){ rs[w]=s; rq[w]=q; }
    __syncthreads();
    float S = rs[0]+rs[1]+rs[2]+rs[3];
    float Q = rq[0]+rq[1]+rq[2]+rq[3];
    float mean = S*(1.0f/DM);
    float var  = Q*(1.0f/DM) - mean*mean;
    float rstd = rsqrtf(var + LN_EPS);
    bf16* hr = h + (size_t)bid*DM;
    hr[t]     = (bf16)((v0-mean)*rstd*gamma[t]     + beta[t]);
    hr[t+256] = (bf16)((v1-mean)*rstd*gamma[t+256] + beta[t+256]);
    hr[t+512] = (bf16)((v2-mean)*rstd*gamma[t+512] + beta[t+512]);
  } else {
    int tb = bid - 4096;
    int z = tb/576, rem = tb%576;
    int r0 = (rem/24)*32, c0 = (rem%24)*32;
    int tx = t&31, ty = t>>5;   // (32,8)
    float (*tile)[33] = (float(*)[33])smem;
    const float* src = (z==0)?Wq:(z==1)?Wk:(z==2)?Wv:Wo;
    #pragma unroll
    for (int i=ty;i<32;i+=8) tile[i][tx] = src[(size_t)(r0+i)*DM + c0+tx];
    __syncthreads();
    bf16* dst = (z<3) ? (Wqkvt + (size_t)z*DM*DM) : Wot;
    #pragma unroll
    for (int i=ty;i<32;i+=8) dst[(size_t)(c0+i)*DM + r0+tx] = (bf16)tile[tx][i];
  }
}

// ---------------- GEMM: C = A * Bt^T, BK=32, 3-buffer counted-vmcnt pipeline -
// EPI 0: QKV epilogue (Q cols scaled LOG2E; V -> V^T [b][h][d][n])
// EPI 1: out fp32 = acc + bo[col] + x[row][col]
template<int BM, int BN, int WM, int WN, int EPI>
__global__ __launch_bounds__(256) void gemm_bt(
    const bf16* __restrict__ A, const bf16* __restrict__ Bt, int K,
    bf16* __restrict__ qk, bf16* __restrict__ vt,
    float* __restrict__ out, const float* __restrict__ bo, const float* __restrict__ xres)
{
  constexpr int MF = BM/(WM*16);
  constexpr int NF = BN/(WN*16);
  constexpr int GL = BM/64 + BN/64;   // gloads per wave per stage
  __shared__ bf16 As[3][BM][32];
  __shared__ bf16 Bs[3][BN][32];
  int tid = threadIdx.x, w = tid>>6, la = tid&63;
  int bn = blockIdx.x, bm = blockIdx.y;
  int wm = w / WN, wn = w % WN;
  int g = la>>4, li = la&15;
  int sr = la>>2, sc = (la&3)*8;      // staging: 4 lanes per 32-elem row
  f32x4 acc[MF][NF] = {};
  const int KT = K/32;

  auto stage = [&](int kt, int bb) {
    int k0 = kt*32;
    #pragma unroll
    for (int i=0;i<BM/64;i++){ int r0 = i*64 + w*16;
      gload16(A + ((size_t)(bm*BM + r0 + sr))*K + k0 + sc, &As[bb][r0][0]); }
    #pragma unroll
    for (int i=0;i<BN/64;i++){ int r0 = i*64 + w*16;
      gload16(Bt + ((size_t)(bn*BN + r0 + sr))*K + k0 + sc, &Bs[bb][r0][0]); }
  };

  stage(0,0); stage(1,1);
  asm volatile("s_waitcnt vmcnt(%0)" :: "n"(GL) : "memory");
  __builtin_amdgcn_s_barrier();
  __builtin_amdgcn_sched_barrier(0);

  for (int kt=0; kt<KT; ++kt) {
    int bb = kt%3;
    if (kt+2 < KT) stage(kt+2, (kt+2)%3);
    bf16x8 af[MF], bfr[NF];
    #pragma unroll
    for (int i=0;i<MF;i++) af[i]  = *(const bf16x8*)&As[bb][wm*(BM/WM)+i*16+li][g*8];
    #pragma unroll
    for (int j=0;j<NF;j++) bfr[j] = *(const bf16x8*)&Bs[bb][wn*(BN/WN)+j*16+li][g*8];
    __builtin_amdgcn_s_setprio(1);
    #pragma unroll
    for (int i=0;i<MF;i++)
      #pragma unroll
      for (int j=0;j<NF;j++)
        acc[i][j] = __builtin_amdgcn_mfma_f32_16x16x32_bf16(af[i], bfr[j], acc[i][j], 0,0,0);
    __builtin_amdgcn_s_setprio(0);
    if (kt+1 < KT) {
      if (kt+2 < KT) asm volatile("s_waitcnt vmcnt(%0)" :: "n"(GL) : "memory");
      else           asm volatile("s_waitcnt vmcnt(0)" ::: "memory");
      __builtin_amdgcn_s_barrier();
      __builtin_amdgcn_sched_barrier(0);
    }
  }

  #pragma unroll
  for (int i=0;i<MF;i++){
    int row0 = bm*BM + wm*(BM/WM) + i*16 + g*4;
    #pragma unroll
    for (int j=0;j<NF;j++){
      int col = bn*BN + wn*(BN/WN) + j*16 + li;
      if (EPI==0){
        if (col < 1536) {
          float qs = (col < 768) ? LOG2E : 1.0f;   // uniform per j-tile (768%BN==0)
          #pragma unroll
          for (int r=0;r<4;r++) qk[(size_t)(row0+r)*1536 + col] = (bf16)(acc[i][j][r]*qs);
        } else {
          int cv = col - 1536; int hh = cv>>6, dd = cv&63;
          int b_ = row0>>11,  n0 = row0&2047;
          u16x4 u;
          #pragma unroll
          for (int r=0;r<4;r++){ bf16 bv = (bf16)acc[i][j][r];
            u[r] = __builtin_bit_cast(unsigned short, bv); }
          *reinterpret_cast<u16x4*>(vt + ((size_t)((b_*NH+hh)*HD+dd))*SEQ + n0) = u;
        }
      } else {
        float bb2 = bo[col];
        #pragma unroll
        for (int r=0;r<4;r++){ size_t idx = (size_t)(row0+r)*DM + col;
          out[idx] = acc[i][j][r] + bb2 + xres[idx]; }
      }
    }
  }
}

// ---------------- flash attention: 16q/wave + KV-split, occupancy-tuned -----
// Occupancy model (m69 + rounds 6-10): waves/CU cap halves when combined
// VGPR+AGPR crosses 128. Rounds 9/10 (132-136 regs) capped at 8 waves/CU;
// rounds 6/7 (<=84 regs, cap 16) were GRID-limited at 768 blocks = 3/CU.
// This config finally exercises the 16-wave cap: 16q/wave (regs ~72),
// 2-buffer 32KB LDS (5 blocks/CU), KV-split x2 -> grid 1536 = 6 blocks/CU
// -> ~4 resident blocks = 16 waves/CU, 2x rounds 6/7, 3x round 10.
// Static-max softmax is exactly additive across KV halves: raw partial O
// (bf16) -> d_out (dead until GEMM2), partial l -> ws; reduce merges.
// Swapped QK keeps P lane-local (q = li); P->PV-B-frag via cvt_pk +
// permlane32/16 transposes (reg0 word as vdst).
__global__ __launch_bounds__(256) void attn_kernel(
    const bf16* __restrict__ QK, const bf16* __restrict__ Vt,
    bf16* __restrict__ Opart, float* __restrict__ lpart)
{
  __shared__ bf16 Ks[2][64][64];
  __shared__ bf16 Vs[2][64][64];   // V^T tile: [d][kv]
  int tid=threadIdx.x, w=tid>>6, la=tid&63;
  int id = blockIdx.x;
  int xcd = id & 7, idx = id >> 3;       // 1536 = 8 * 192, bijective
  int bh  = xcd*3 + idx/64;              // 3 (b,h) per XCD -> K/V L2-resident
  int rem = idx & 63;
  int qt  = rem >> 1;                    // 0..31 (64-q tiles)
  int kvh = rem & 1;                     // KV half
  int b = bh/NH, hh = bh%NH;
  int g=la>>4, li=la&15;
  int lr=la>>3;
  int lx=li&7;
  int lcs=((la&7)^lr)*8;           // swizzled source column (elements)
  size_t qrow0=(size_t)b*SEQ + qt*64;
  int kv0 = kvh*1024;

  // Q frags (B-operand: Q[q=li][k]), pre-scaled by LOG2E in GEMM1; registers
  bf16x8 qf[2];
  {
    const bf16* qp = QK + (qrow0 + w*16 + li)*1536 + hh*64;
    qf[0] = *(const bf16x8*)(qp + g*8);
    qf[1] = *(const bf16x8*)(qp + 32 + g*8);
  }

  const bf16* Kbase = QK + (size_t)b*SEQ*1536 + 768 + hh*64;
  const bf16* Vbase = Vt + (size_t)(b*NH+hh)*HD*SEQ;

  auto stage = [&](int tt, int bb) {
    int j0 = kv0 + tt*64;
    #pragma unroll
    for (int i=0;i<2;i++){ int c=i*4+w;
      gload16(Kbase + (size_t)(j0 + c*8 + lr)*1536 + lcs, &Ks[bb][c*8][0]);
      gload16(Vbase + (size_t)(c*8 + lr)*SEQ + j0 + lcs,  &Vs[bb][c*8][0]); }
  };

  stage(0,0);
  asm volatile("s_waitcnt vmcnt(0)" ::: "memory");
  __builtin_amdgcn_s_barrier();
  __builtin_amdgcn_sched_barrier(0);

  f32x4 o[4] = {};
  float lp[4] = {0.f,0.f,0.f,0.f};

  for (int t=0;t<16;t++){
    int bb = t&1;
    if (t+1 < 16) stage(t+1, bb^1);
    // S = K Q^T (swapped): lane holds S[kv=nf*16+g*4+r][q=li]
    f32x4 s[4] = {};
    #pragma unroll
    for (int kk=0;kk<2;kk++){
      bf16x8 kf[4];
      #pragma unroll
      for (int nf=0;nf<4;nf++){
        int row = nf*16+li;
        kf[nf] = *(const bf16x8*)((const char*)&Ks[bb][0][0] + row*128 + (((kk*4+g)^lx)<<4));
      }
      __builtin_amdgcn_s_setprio(1);
      #pragma unroll
      for (int nf=0;nf<4;nf++)
        s[nf] = __builtin_amdgcn_mfma_f32_16x16x32_bf16(kf[nf], qf[kk], s[nf], 0,0,0);
      __builtin_amdgcn_s_setprio(0);
    }
    // static-max softmax: p = 2^s, lane-local (q = li); 4 partial-sum chains
    float p[4][4];
    #pragma unroll
    for (int nf=0;nf<4;nf++){
      #pragma unroll
      for (int r=0;r<4;r++){
        p[nf][r] = __builtin_amdgcn_exp2f(s[nf][r]);
        lp[nf] += p[nf][r];
      }
    }
    // in-register exchange: PV B-frags pa[ks] = P[kv][q=li]
    bf16x8 pa[2];
    #pragma unroll
    for (int ks=0;ks<2;ks++){
      unsigned int c00,c01,c10,c11;
      asm("v_cvt_pk_bf16_f32 %0, %1, %2" : "=v"(c00) : "v"(p[2*ks  ][0]), "v"(p[2*ks  ][1]));
      asm("v_cvt_pk_bf16_f32 %0, %1, %2" : "=v"(c01) : "v"(p[2*ks  ][2]), "v"(p[2*ks  ][3]));
      asm("v_cvt_pk_bf16_f32 %0, %1, %2" : "=v"(c10) : "v"(p[2*ks+1][0]), "v"(p[2*ks+1][1]));
      asm("v_cvt_pk_bf16_f32 %0, %1, %2" : "=v"(c11) : "v"(p[2*ks+1][2]), "v"(p[2*ks+1][3]));
      // transpose (reg-bit, lane-b5) then (reg-bit, lane-b4); reg0 word = vdst
      asm("v_permlane32_swap_b32 %0, %1" : "+v"(c00), "+v"(c10));
      asm("v_permlane32_swap_b32 %0, %1" : "+v"(c01), "+v"(c11));
      asm("v_permlane16_swap_b32 %0, %1" : "+v"(c00), "+v"(c10));
      asm("v_permlane16_swap_b32 %0, %1" : "+v"(c01), "+v"(c11));
      u32x4v cc = {c00, c01, c10, c11};
      pa[ks] = __builtin_bit_cast(bf16x8, cc);
    }
    // PV: O[d][q] += V^T[d][kv] * P[kv][q]
    #pragma unroll
    for (int ks=0;ks<2;ks++){
      bf16x8 vb[4];
      #pragma unroll
      for (int df=0;df<4;df++){
        int row = df*16+li;
        vb[df] = *(const bf16x8*)((const char*)&Vs[bb][0][0] + row*128 + (((ks*4+g)^lx)<<4));
      }
      __builtin_amdgcn_s_setprio(1);
      #pragma unroll
      for (int df=0;df<4;df++)
        o[df] = __builtin_amdgcn_mfma_f32_16x16x32_bf16(vb[df], pa[ks], o[df], 0,0,0);
      __builtin_amdgcn_s_setprio(0);
    }
    if (t+1 < 16) {
      asm volatile("s_waitcnt vmcnt(0)" ::: "memory");
      __builtin_amdgcn_s_barrier();
      __builtin_amdgcn_sched_barrier(0);
    }
  }
  // raw partials. lane holds O[d=df*16+g*4+r][q=li]; l = sum over g-quarters
  float lsum = lp[0]+lp[1]+lp[2]+lp[3];
  lsum += __shfl_xor(lsum, 16, 64);
  lsum += __shfl_xor(lsum, 32, 64);
  bf16* ob = Opart + (size_t)kvh*4096*DM;
  size_t row = qrow0 + w*16 + li;
  #pragma unroll
  for (int df=0;df<4;df++){
    u16x4 u;
    #pragma unroll
    for (int r=0;r<4;r++){
      bf16 bv = (bf16)o[df][r];
      u[r] = __builtin_bit_cast(unsigned short, bv);
    }
    *reinterpret_cast<u16x4*>(ob + row*DM + hh*64 + df*16 + g*4) = u;
  }
  if (g==0) lpart[(size_t)kvh*24*SEQ + (size_t)bh*SEQ + qt*64 + w*16 + li] = lsum;
}

// ---------------- reduce: vals = (O_a + O_b) * SCALE / (l_a + l_b) ----------
__global__ __launch_bounds__(256) void reduce_kernel(
    const bf16* __restrict__ Op, const float* __restrict__ lp, bf16* __restrict__ vals)
{
  int gid = blockIdx.x*256 + threadIdx.x;   // 0..393215 (4096 rows x 96 vec8)
  int r = gid/96, cv = gid - r*96;
  int c0 = cv*8;
  int b = r>>11, q = r&2047, h = c0>>6;
  size_t li = (size_t)(b*NH + h)*SEQ + q;
  float l = lp[li] + lp[(size_t)24*SEQ + li];
  float fac = ATT_SCALE / l;
  bf16x8 a = *(const bf16x8*)(Op + (size_t)r*DM + c0);
  bf16x8 bb = *(const bf16x8*)(Op + (size_t)4096*DM + (size_t)r*DM + c0);
  bf16x8 o;
  #pragma unroll
  for (int i=0;i<8;i++) o[i] = (bf16)(((float)a[i] + (float)bb[i]) * fac);
  *(bf16x8*)(vals + (size_t)r*DM + c0) = o;
}

// ---------------- launch -----------------------------------------------------
extern "C" void kernel_launch(void* const* d_in, const int* in_sizes, int n_in,
                              void* d_out, int out_size, void* d_ws, size_t ws_size,
                              hipStream_t stream)
{
  const float* x     = (const float*)d_in[0];
  const float* Wq    = (const float*)d_in[1];
  const float* Wk    = (const float*)d_in[2];
  const float* Wv    = (const float*)d_in[3];
  const float* Wo    = (const float*)d_in[4];
  const float* bo    = (const float*)d_in[5];
  const float* gamma = (const float*)d_in[6];
  const float* beta  = (const float*)d_in[7];
  float* out = (float*)d_out;
  char* ws = (char*)d_ws;

  bf16* h     = (bf16*)(ws + 0);          // 4096*768*2    = 6291456
  bf16* vals  = (bf16*)(ws + 0);          // alias of h (h dead after GEMM1)
  bf16* Wqkvt = (bf16*)(ws + 6291456);    // 2304*768*2    = 3538944
  bf16* Wot   = (bf16*)(ws + 9830400);    // 768*768*2     = 1179648
  bf16* QKb   = (bf16*)(ws + 11010048);   // 4096*1536*2   = 12582912
  bf16* Vt    = (bf16*)(ws + 23592960);   // 24*64*2048*2  = 6291456
  // partials: Opart -> d_out (2 x bf16 [4096][768] = exactly its 12.58MB,
  // dead until GEMM2 overwrites); lpart -> dead Wqkvt region (393KB,
  // Wqkvt only read by GEMM1 which completes before attn).
  bf16*  Opart = (bf16*)d_out;
  float* lpart = (float*)(ws + 6291456);
  (void)ws_size; (void)in_sizes; (void)n_in; (void)out_size;

  prep_kernel<<<dim3(6400), dim3(256), 0, stream>>>(
      x, gamma, beta, h, Wq, Wk, Wv, Wo, Wqkvt, Wot);
  gemm_bt<128,128,2,2,0><<<dim3(18,32), dim3(256), 0, stream>>>(
      h, Wqkvt, DM, QKb, Vt, nullptr, nullptr, nullptr);
  attn_kernel<<<dim3(1536), dim3(256), 0, stream>>>(QKb, Vt, Opart, lpart);
  reduce_kernel<<<dim3(1536), dim3(256), 0, stream>>>(Opart, lpart, vals);
  gemm_bt<64,64,2,2,1><<<dim3(12,64), dim3(256), 0, stream>>>(
      vals, Wot, DM, nullptr, nullptr, out, bo, x);
}

// Round 12
// 104.092 us; speedup vs baseline: 1.1157x; 1.0300x over previous
//
#include <hip/hip_runtime.h>
#include <stdint.h>

typedef __bf16 bf16;
typedef __bf16 bf16x8 __attribute__((ext_vector_type(8)));
typedef float  f32x4  __attribute__((ext_vector_type(4)));
typedef unsigned short u16x4 __attribute__((ext_vector_type(4)));
typedef unsigned int   u32x4v __attribute__((ext_vector_type(4)));

#define SEQ   2048
#define DM    768
#define NH    12
#define HD    64
#define ATT_SCALE 0.125f
#define LOG2E 1.44269504f
#define LN_EPS 1e-5f

// async global->LDS, 16B per lane; LDS dest is wave-uniform base + lane*16
__device__ __forceinline__ void gload16(const void* g, void* l) {
  __builtin_amdgcn_global_load_lds((const __attribute__((address_space(1))) void*)g,
                                   (__attribute__((address_space(3))) void*)l,
                                   16, 0, 0);
}

// ---------------- prep: LN (blocks 0..4095) + weight transpose (4096..6399) -
__global__ __launch_bounds__(256) void prep_kernel(
    const float* __restrict__ x, const float* __restrict__ gamma,
    const float* __restrict__ beta, bf16* __restrict__ h,
    const float* __restrict__ Wq, const float* __restrict__ Wk,
    const float* __restrict__ Wv, const float* __restrict__ Wo,
    bf16* __restrict__ Wqkvt, bf16* __restrict__ Wot)
{
  __shared__ float smem[32*33];
  int bid = blockIdx.x, t = threadIdx.x;
  if (bid < 4096) {
    const float* xr = x + (size_t)bid*DM;
    float v0 = xr[t], v1 = xr[t+256], v2 = xr[t+512];
    float s = v0+v1+v2;
    float q = v0*v0+v1*v1+v2*v2;
    #pragma unroll
    for (int m=32;m>=1;m>>=1){ s += __shfl_xor(s,m,64); q += __shfl_xor(q,m,64); }
    float* rs = smem; float* rq = smem+8;
    int w = t>>6;
    if ((t&63)==0){ rs[w]=s; rq[w]=q; }
    __syncthreads();
    float S = rs[0]+rs[1]+rs[2]+rs[3];
    float Q = rq[0]+rq[1]+rq[2]+rq[3];
    float mean = S*(1.0f/DM);
    float var  = Q*(1.0f/DM) - mean*mean;
    float rstd = rsqrtf(var + LN_EPS);
    bf16* hr = h + (size_t)bid*DM;
    hr[t]     = (bf16)((v0-mean)*rstd*gamma[t]     + beta[t]);
    hr[t+256] = (bf16)((v1-mean)*rstd*gamma[t+256] + beta[t+256]);
    hr[t+512] = (bf16)((v2-mean)*rstd*gamma[t+512] + beta[t+512]);
  } else {
    int tb = bid - 4096;
    int z = tb/576, rem = tb%576;
    int r0 = (rem/24)*32, c0 = (rem%24)*32;
    int tx = t&31, ty = t>>5;   // (32,8)
    float (*tile)[33] = (float(*)[33])smem;
    const float* src = (z==0)?Wq:(z==1)?Wk:(z==2)?Wv:Wo;
    #pragma unroll
    for (int i=ty;i<32;i+=8) tile[i][tx] = src[(size_t)(r0+i)*DM + c0+tx];
    __syncthreads();
    bf16* dst = (z<3) ? (Wqkvt + (size_t)z*DM*DM) : Wot;
    #pragma unroll
    for (int i=ty;i<32;i+=8) dst[(size_t)(c0+i)*DM + r0+tx] = (bf16)tile[tx][i];
  }
}

// ---------------- GEMM: C = A * Bt^T, BK=32, 3-buffer counted-vmcnt pipeline -
// EPI 0: QKV epilogue (Q cols scaled LOG2E; V -> V^T [b][h][d][n])
// EPI 1: out fp32 = acc + bo[col] + x[row][col]
template<int BM, int BN, int WM, int WN, int EPI>
__global__ __launch_bounds__(256) void gemm_bt(
    const bf16* __restrict__ A, const bf16* __restrict__ Bt, int K,
    bf16* __restrict__ qk, bf16* __restrict__ vt,
    float* __restrict__ out, const float* __restrict__ bo, const float* __restrict__ xres)
{
  constexpr int MF = BM/(WM*16);
  constexpr int NF = BN/(WN*16);
  constexpr int GL = BM/64 + BN/64;   // gloads per wave per stage
  __shared__ bf16 As[3][BM][32];
  __shared__ bf16 Bs[3][BN][32];
  int tid = threadIdx.x, w = tid>>6, la = tid&63;
  int bn = blockIdx.x, bm = blockIdx.y;
  int wm = w / WN, wn = w % WN;
  int g = la>>4, li = la&15;
  int sr = la>>2, sc = (la&3)*8;      // staging: 4 lanes per 32-elem row
  f32x4 acc[MF][NF] = {};
  const int KT = K/32;

  auto stage = [&](int kt, int bb) {
    int k0 = kt*32;
    #pragma unroll
    for (int i=0;i<BM/64;i++){ int r0 = i*64 + w*16;
      gload16(A + ((size_t)(bm*BM + r0 + sr))*K + k0 + sc, &As[bb][r0][0]); }
    #pragma unroll
    for (int i=0;i<BN/64;i++){ int r0 = i*64 + w*16;
      gload16(Bt + ((size_t)(bn*BN + r0 + sr))*K + k0 + sc, &Bs[bb][r0][0]); }
  };

  stage(0,0); stage(1,1);
  asm volatile("s_waitcnt vmcnt(%0)" :: "n"(GL) : "memory");
  __builtin_amdgcn_s_barrier();
  __builtin_amdgcn_sched_barrier(0);

  for (int kt=0; kt<KT; ++kt) {
    int bb = kt%3;
    if (kt+2 < KT) stage(kt+2, (kt+2)%3);
    bf16x8 af[MF], bfr[NF];
    #pragma unroll
    for (int i=0;i<MF;i++) af[i]  = *(const bf16x8*)&As[bb][wm*(BM/WM)+i*16+li][g*8];
    #pragma unroll
    for (int j=0;j<NF;j++) bfr[j] = *(const bf16x8*)&Bs[bb][wn*(BN/WN)+j*16+li][g*8];
    __builtin_amdgcn_s_setprio(1);
    #pragma unroll
    for (int i=0;i<MF;i++)
      #pragma unroll
      for (int j=0;j<NF;j++)
        acc[i][j] = __builtin_amdgcn_mfma_f32_16x16x32_bf16(af[i], bfr[j], acc[i][j], 0,0,0);
    __builtin_amdgcn_s_setprio(0);
    if (kt+1 < KT) {
      if (kt+2 < KT) asm volatile("s_waitcnt vmcnt(%0)" :: "n"(GL) : "memory");
      else           asm volatile("s_waitcnt vmcnt(0)" ::: "memory");
      __builtin_amdgcn_s_barrier();
      __builtin_amdgcn_sched_barrier(0);
    }
  }

  #pragma unroll
  for (int i=0;i<MF;i++){
    int row0 = bm*BM + wm*(BM/WM) + i*16 + g*4;
    #pragma unroll
    for (int j=0;j<NF;j++){
      int col = bn*BN + wn*(BN/WN) + j*16 + li;
      if (EPI==0){
        if (col < 1536) {
          float qs = (col < 768) ? LOG2E : 1.0f;   // uniform per j-tile (768%BN==0)
          #pragma unroll
          for (int r=0;r<4;r++) qk[(size_t)(row0+r)*1536 + col] = (bf16)(acc[i][j][r]*qs);
        } else {
          int cv = col - 1536; int hh = cv>>6, dd = cv&63;
          int b_ = row0>>11,  n0 = row0&2047;
          u16x4 u;
          #pragma unroll
          for (int r=0;r<4;r++){ bf16 bv = (bf16)acc[i][j][r];
            u[r] = __builtin_bit_cast(unsigned short, bv); }
          *reinterpret_cast<u16x4*>(vt + ((size_t)((b_*NH+hh)*HD+dd))*SEQ + n0) = u;
        }
      } else {
        float bb2 = bo[col];
        #pragma unroll
        for (int r=0;r<4;r++){ size_t idx = (size_t)(row0+r)*DM + col;
          out[idx] = acc[i][j][r] + bb2 + xres[idx]; }
      }
    }
  }
}

// ---------------- flash attention: in-block KV-split, 512 threads -----------
// One block = 8 waves over a 64-q tile: waves 0-3 (half 0) process
// kv[0,1024), waves 4-7 (half 1) kv[1024,2048) — identical 16q/wave pipelines
// in separate LDS double-buffers; the shared s_barrier lockstep is harmless
// (identical schedules). Static-max softmax is exactly additive across
// halves, so the merge is O0+O1 and l0+l1: half 1 spills O (bf16, swizzled)
// + l to LDS, one barrier, half 0 merges in-register and writes vals.
// vs rounds 9-11: same KV-split parallelism (16 waves/CU at the VGPR-60 cap:
// 2 blocks x 8 waves, 73.9KB LDS) but NO reduce kernel, no partial-O HBM
// round-trip (~31MB), no extra launch gap.
// Swapped QK keeps P lane-local (q=li); P->PV-B-frag via cvt_pk +
// permlane32/16 transposes (reg0 word as vdst). XCD-pinned block map.
__global__ __launch_bounds__(512) void attn_kernel(
    const bf16* __restrict__ QK, const bf16* __restrict__ Vt,
    bf16* __restrict__ vals)
{
  __shared__ bf16 Ks[2][2][64][64];   // [half][buf][row][col]
  __shared__ bf16 Vs[2][2][64][64];   // V^T tiles: [d][kv]
  __shared__ bf16 Om[4][16][64];      // half-1 partial O: [wave][q][d] (swizzled)
  __shared__ float lm[64];            // half-1 partial l per q-row
  int tid=threadIdx.x, w=tid>>6, la=tid&63;
  int half = w>>2, wl = w&3;
  int id = blockIdx.x;
  int xcd = id & 7, idx = id >> 3;       // 768 = 8 * 96, bijective
  int bh  = xcd*3 + idx/32;              // 3 (b,h) per XCD -> K/V L2-resident
  int qt  = idx & 31;
  int b = bh/NH, hh = bh%NH;
  int g=la>>4, li=la&15;
  int lr=la>>3;
  int lx=li&7;
  int lcs=((la&7)^lr)*8;           // swizzled source column (elements)
  size_t qrow0=(size_t)b*SEQ + qt*64;
  int kv0 = half*1024;

  // Q frags (B-operand: Q[q=li][k]), pre-scaled by LOG2E in GEMM1; registers
  bf16x8 qf[2];
  {
    const bf16* qp = QK + (qrow0 + wl*16 + li)*1536 + hh*64;
    qf[0] = *(const bf16x8*)(qp + g*8);
    qf[1] = *(const bf16x8*)(qp + 32 + g*8);
  }

  const bf16* Kbase = QK + (size_t)b*SEQ*1536 + 768 + hh*64;
  const bf16* Vbase = Vt + (size_t)(b*NH+hh)*HD*SEQ;

  auto stage = [&](int tt, int bbuf) {
    int j0 = kv0 + tt*64;
    #pragma unroll
    for (int i=0;i<2;i++){ int c=i*4+wl;
      gload16(Kbase + (size_t)(j0 + c*8 + lr)*1536 + lcs, &Ks[half][bbuf][c*8][0]);
      gload16(Vbase + (size_t)(c*8 + lr)*SEQ + j0 + lcs,  &Vs[half][bbuf][c*8][0]); }
  };

  stage(0,0);
  asm volatile("s_waitcnt vmcnt(0)" ::: "memory");
  __builtin_amdgcn_s_barrier();
  __builtin_amdgcn_sched_barrier(0);

  f32x4 o[4] = {};
  float lp[4] = {0.f,0.f,0.f,0.f};

  for (int t=0;t<16;t++){
    int bb = t&1;
    if (t+1 < 16) stage(t+1, bb^1);
    // S = K Q^T (swapped): lane holds S[kv=nf*16+g*4+r][q=li]
    f32x4 s[4] = {};
    #pragma unroll
    for (int kk=0;kk<2;kk++){
      bf16x8 kf[4];
      #pragma unroll
      for (int nf=0;nf<4;nf++){
        int row = nf*16+li;
        kf[nf] = *(const bf16x8*)((const char*)&Ks[half][bb][0][0] + row*128 + (((kk*4+g)^lx)<<4));
      }
      __builtin_amdgcn_s_setprio(1);
      #pragma unroll
      for (int nf=0;nf<4;nf++)
        s[nf] = __builtin_amdgcn_mfma_f32_16x16x32_bf16(kf[nf], qf[kk], s[nf], 0,0,0);
      __builtin_amdgcn_s_setprio(0);
    }
    // static-max softmax: p = 2^s, lane-local (q = li)
    float p[4][4];
    #pragma unroll
    for (int nf=0;nf<4;nf++){
      #pragma unroll
      for (int r=0;r<4;r++){
        p[nf][r] = __builtin_amdgcn_exp2f(s[nf][r]);
        lp[nf] += p[nf][r];
      }
    }
    // in-register exchange: PV B-frags pa[ks] = P[kv][q=li]
    bf16x8 pa[2];
    #pragma unroll
    for (int ks=0;ks<2;ks++){
      unsigned int c00,c01,c10,c11;
      asm("v_cvt_pk_bf16_f32 %0, %1, %2" : "=v"(c00) : "v"(p[2*ks  ][0]), "v"(p[2*ks  ][1]));
      asm("v_cvt_pk_bf16_f32 %0, %1, %2" : "=v"(c01) : "v"(p[2*ks  ][2]), "v"(p[2*ks  ][3]));
      asm("v_cvt_pk_bf16_f32 %0, %1, %2" : "=v"(c10) : "v"(p[2*ks+1][0]), "v"(p[2*ks+1][1]));
      asm("v_cvt_pk_bf16_f32 %0, %1, %2" : "=v"(c11) : "v"(p[2*ks+1][2]), "v"(p[2*ks+1][3]));
      // transpose (reg-bit, lane-b5) then (reg-bit, lane-b4); reg0 word = vdst
      asm("v_permlane32_swap_b32 %0, %1" : "+v"(c00), "+v"(c10));
      asm("v_permlane32_swap_b32 %0, %1" : "+v"(c01), "+v"(c11));
      asm("v_permlane16_swap_b32 %0, %1" : "+v"(c00), "+v"(c10));
      asm("v_permlane16_swap_b32 %0, %1" : "+v"(c01), "+v"(c11));
      u32x4v cc = {c00, c01, c10, c11};
      pa[ks] = __builtin_bit_cast(bf16x8, cc);
    }
    // PV: O[d][q] += V^T[d][kv] * P[kv][q]
    #pragma unroll
    for (int ks=0;ks<2;ks++){
      bf16x8 vb[4];
      #pragma unroll
      for (int df=0;df<4;df++){
        int row = df*16+li;
        vb[df] = *(const bf16x8*)((const char*)&Vs[half][bb][0][0] + row*128 + (((ks*4+g)^lx)<<4));
      }
      __builtin_amdgcn_s_setprio(1);
      #pragma unroll
      for (int df=0;df<4;df++)
        o[df] = __builtin_amdgcn_mfma_f32_16x16x32_bf16(vb[df], pa[ks], o[df], 0,0,0);
      __builtin_amdgcn_s_setprio(0);
    }
    if (t+1 < 16) {
      asm volatile("s_waitcnt vmcnt(0)" ::: "memory");
      __builtin_amdgcn_s_barrier();
      __builtin_amdgcn_sched_barrier(0);
    }
  }
  // merge halves. lane holds O[d=df*16+g*4+r][q=li]; lsum = row sum (q=li)
  float lsum = lp[0]+lp[1]+lp[2]+lp[3];
  lsum += __shfl_xor(lsum, 16, 64);
  lsum += __shfl_xor(lsum, 32, 64);
  int swz = (li&7)<<4;
  if (half==1){
    char* om = (char*)&Om[wl][0][0];
    #pragma unroll
    for (int df=0;df<4;df++){
      u16x4 u;
      #pragma unroll
      for (int r=0;r<4;r++){
        bf16 bv = (bf16)o[df][r];
        u[r] = __builtin_bit_cast(unsigned short, bv);
      }
      *reinterpret_cast<u16x4*>(om + li*128 + ((df*32 + g*8) ^ swz)) = u;
    }
    if (g==0) lm[wl*16+li] = lsum;
  }
  __syncthreads();
  if (half==0){
    const char* om = (const char*)&Om[wl][0][0];
    float ltot = lsum + lm[wl*16+li];
    float fac = ATT_SCALE / ltot;
    bf16* vrow = vals + (qrow0 + wl*16 + li)*DM + hh*64;
    #pragma unroll
    for (int df=0;df<4;df++){
      u16x4 pu = *reinterpret_cast<const u16x4*>(om + li*128 + ((df*32 + g*8) ^ swz));
      u16x4 u;
      #pragma unroll
      for (int r=0;r<4;r++){
        float pv = (float)__builtin_bit_cast(bf16, pu[r]);
        bf16 bv = (bf16)((o[df][r] + pv) * fac);
        u[r] = __builtin_bit_cast(unsigned short, bv);
      }
      *reinterpret_cast<u16x4*>(vrow + df*16 + g*4) = u;
    }
  }
}

// ---------------- launch -----------------------------------------------------
extern "C" void kernel_launch(void* const* d_in, const int* in_sizes, int n_in,
                              void* d_out, int out_size, void* d_ws, size_t ws_size,
                              hipStream_t stream)
{
  const float* x     = (const float*)d_in[0];
  const float* Wq    = (const float*)d_in[1];
  const float* Wk    = (const float*)d_in[2];
  const float* Wv    = (const float*)d_in[3];
  const float* Wo    = (const float*)d_in[4];
  const float* bo    = (const float*)d_in[5];
  const float* gamma = (const float*)d_in[6];
  const float* beta  = (const float*)d_in[7];
  float* out = (float*)d_out;
  char* ws = (char*)d_ws;

  bf16* h     = (bf16*)(ws + 0);          // 4096*768*2    = 6291456
  bf16* vals  = (bf16*)(ws + 0);          // alias of h (h dead after GEMM1)
  bf16* Wqkvt = (bf16*)(ws + 6291456);    // 2304*768*2    = 3538944
  bf16* Wot   = (bf16*)(ws + 9830400);    // 768*768*2     = 1179648
  bf16* QKb   = (bf16*)(ws + 11010048);   // 4096*1536*2   = 12582912
  bf16* Vt    = (bf16*)(ws + 23592960);   // 24*64*2048*2  = 6291456
  (void)ws_size; (void)in_sizes; (void)n_in; (void)out_size;

  prep_kernel<<<dim3(6400), dim3(256), 0, stream>>>(
      x, gamma, beta, h, Wq, Wk, Wv, Wo, Wqkvt, Wot);
  gemm_bt<128,128,2,2,0><<<dim3(18,32), dim3(256), 0, stream>>>(
      h, Wqkvt, DM, QKb, Vt, nullptr, nullptr, nullptr);
  attn_kernel<<<dim3(768), dim3(512), 0, stream>>>(QKb, Vt, vals);
  gemm_bt<64,64,2,2,1><<<dim3(12,64), dim3(256), 0, stream>>>(
      vals, Wot, DM, nullptr, nullptr, out, bo, x);
}

// Round 13
// 102.643 us; speedup vs baseline: 1.1314x; 1.0141x over previous
//
#include <hip/hip_runtime.h>
#include <stdint.h>

typedef __bf16 bf16;
typedef __bf16 bf16x8 __attribute__((ext_vector_type(8)));
typedef float  f32x4  __attribute__((ext_vector_type(4)));
typedef unsigned short u16x4 __attribute__((ext_vector_type(4)));
typedef unsigned int   u32x4v __attribute__((ext_vector_type(4)));

#define SEQ   2048
#define DM    768
#define NH    12
#define HD    64
#define ATT_SCALE 0.125f
#define LOG2E 1.44269504f
#define LN_EPS 1e-5f

// async global->LDS, 16B per lane; LDS dest is wave-uniform base + lane*16
__device__ __forceinline__ void gload16(const void* g, void* l) {
  __builtin_amdgcn_global_load_lds((const __attribute__((address_space(1))) void*)g,
                                   (__attribute__((address_space(3))) void*)l,
                                   16, 0, 0);
}

// ---------------- prep: LN (blocks 0..4095) + weight transpose (4096..6399) -
__global__ __launch_bounds__(256) void prep_kernel(
    const float* __restrict__ x, const float* __restrict__ gamma,
    const float* __restrict__ beta, bf16* __restrict__ h,
    const float* __restrict__ Wq, const float* __restrict__ Wk,
    const float* __restrict__ Wv, const float* __restrict__ Wo,
    bf16* __restrict__ Wqkvt, bf16* __restrict__ Wot)
{
  __shared__ float smem[32*33];
  int bid = blockIdx.x, t = threadIdx.x;
  if (bid < 4096) {
    const float* xr = x + (size_t)bid*DM;
    float v0 = xr[t], v1 = xr[t+256], v2 = xr[t+512];
    float s = v0+v1+v2;
    float q = v0*v0+v1*v1+v2*v2;
    #pragma unroll
    for (int m=32;m>=1;m>>=1){ s += __shfl_xor(s,m,64); q += __shfl_xor(q,m,64); }
    float* rs = smem; float* rq = smem+8;
    int w = t>>6;
    if ((t&63)==0){ rs[w]=s; rq[w]=q; }
    __syncthreads();
    float S = rs[0]+rs[1]+rs[2]+rs[3];
    float Q = rq[0]+rq[1]+rq[2]+rq[3];
    float mean = S*(1.0f/DM);
    float var  = Q*(1.0f/DM) - mean*mean;
    float rstd = rsqrtf(var + LN_EPS);
    bf16* hr = h + (size_t)bid*DM;
    hr[t]     = (bf16)((v0-mean)*rstd*gamma[t]     + beta[t]);
    hr[t+256] = (bf16)((v1-mean)*rstd*gamma[t+256] + beta[t+256]);
    hr[t+512] = (bf16)((v2-mean)*rstd*gamma[t+512] + beta[t+512]);
  } else {
    int tb = bid - 4096;
    int z = tb/576, rem = tb%576;
    int r0 = (rem/24)*32, c0 = (rem%24)*32;
    int tx = t&31, ty = t>>5;   // (32,8)
    float (*tile)[33] = (float(*)[33])smem;
    const float* src = (z==0)?Wq:(z==1)?Wk:(z==2)?Wv:Wo;
    #pragma unroll
    for (int i=ty;i<32;i+=8) tile[i][tx] = src[(size_t)(r0+i)*DM + c0+tx];
    __syncthreads();
    bf16* dst = (z<3) ? (Wqkvt + (size_t)z*DM*DM) : Wot;
    #pragma unroll
    for (int i=ty;i<32;i+=8) dst[(size_t)(c0+i)*DM + r0+tx] = (bf16)tile[tx][i];
  }
}

// ---------------- GEMM: C = A * Bt^T, templated BK, 3-buffer counted vmcnt --
// EPI 0: QKV epilogue (Q cols scaled LOG2E; V -> V^T [b][h][d][n])
// EPI 1: out fp32 = acc + bo[col] + x[row][col]
template<int BM, int BN, int BK, int WM, int WN, int EPI>
__global__ __launch_bounds__(256) void gemm_bt(
    const bf16* __restrict__ A, const bf16* __restrict__ Bt, int K,
    bf16* __restrict__ qk, bf16* __restrict__ vt,
    float* __restrict__ out, const float* __restrict__ bo, const float* __restrict__ xres)
{
  constexpr int MF  = BM/(WM*16);
  constexpr int NF  = BN/(WN*16);
  constexpr int GL  = (BM+BN)*BK/2048;  // gloads per wave per stage
  constexpr int RPI = 512/BK;           // rows covered per gload16 wave-instr
  constexpr int KKN = BK/32;            // MFMA k-steps per tile
  __shared__ bf16 As[3][BM][BK];
  __shared__ bf16 Bs[3][BN][BK];
  int tid = threadIdx.x, w = tid>>6, la = tid&63;
  int bn = blockIdx.x, bm = blockIdx.y;
  int wm = w / WN, wn = w % WN;
  int g = la>>4, li = la&15;
  int sr = la / (BK/8);                 // staging row within group
  int sc = (la % (BK/8))*8;             // staging col (elements)
  f32x4 acc[MF][NF] = {};
  const int KT = K/BK;

  auto stage = [&](int kt, int bb) {
    int k0 = kt*BK;
    #pragma unroll
    for (int i=0;i<BM/(RPI*4);i++){ int r0 = (i*4+w)*RPI;
      gload16(A + ((size_t)(bm*BM + r0 + sr))*K + k0 + sc, &As[bb][r0][0]); }
    #pragma unroll
    for (int i=0;i<BN/(RPI*4);i++){ int r0 = (i*4+w)*RPI;
      gload16(Bt + ((size_t)(bn*BN + r0 + sr))*K + k0 + sc, &Bs[bb][r0][0]); }
  };

  stage(0,0); stage(1,1);
  asm volatile("s_waitcnt vmcnt(%0)" :: "n"(GL) : "memory");
  __builtin_amdgcn_s_barrier();
  __builtin_amdgcn_sched_barrier(0);

  for (int kt=0; kt<KT; ++kt) {
    int bb = kt%3;
    if (kt+2 < KT) stage(kt+2, (kt+2)%3);
    #pragma unroll
    for (int kk=0;kk<KKN;kk++){
      bf16x8 af[MF], bfr[NF];
      #pragma unroll
      for (int i=0;i<MF;i++) af[i]  = *(const bf16x8*)&As[bb][wm*(BM/WM)+i*16+li][kk*32+g*8];
      #pragma unroll
      for (int j=0;j<NF;j++) bfr[j] = *(const bf16x8*)&Bs[bb][wn*(BN/WN)+j*16+li][kk*32+g*8];
      __builtin_amdgcn_s_setprio(1);
      #pragma unroll
      for (int i=0;i<MF;i++)
        #pragma unroll
        for (int j=0;j<NF;j++)
          acc[i][j] = __builtin_amdgcn_mfma_f32_16x16x32_bf16(af[i], bfr[j], acc[i][j], 0,0,0);
      __builtin_amdgcn_s_setprio(0);
    }
    if (kt+1 < KT) {
      if (kt+2 < KT) asm volatile("s_waitcnt vmcnt(%0)" :: "n"(GL) : "memory");
      else           asm volatile("s_waitcnt vmcnt(0)" ::: "memory");
      __builtin_amdgcn_s_barrier();
      __builtin_amdgcn_sched_barrier(0);
    }
  }

  #pragma unroll
  for (int i=0;i<MF;i++){
    int row0 = bm*BM + wm*(BM/WM) + i*16 + g*4;
    #pragma unroll
    for (int j=0;j<NF;j++){
      int col = bn*BN + wn*(BN/WN) + j*16 + li;
      if (EPI==0){
        if (col < 1536) {
          float qs = (col < 768) ? LOG2E : 1.0f;   // uniform per j-tile (768%BN==0)
          #pragma unroll
          for (int r=0;r<4;r++) qk[(size_t)(row0+r)*1536 + col] = (bf16)(acc[i][j][r]*qs);
        } else {
          int cv = col - 1536; int hh = cv>>6, dd = cv&63;
          int b_ = row0>>11,  n0 = row0&2047;
          u16x4 u;
          #pragma unroll
          for (int r=0;r<4;r++){ bf16 bv = (bf16)acc[i][j][r];
            u[r] = __builtin_bit_cast(unsigned short, bv); }
          *reinterpret_cast<u16x4*>(vt + ((size_t)((b_*NH+hh)*HD+dd))*SEQ + n0) = u;
        }
      } else {
        float bb2 = bo[col];
        #pragma unroll
        for (int r=0;r<4;r++){ size_t idx = (size_t)(row0+r)*DM + col;
          out[idx] = acc[i][j][r] + bb2 + xres[idx]; }
      }
    }
  }
}

// ---------------- flash attention: in-block KV-split, 512 threads -----------
// One block = 8 waves over a 64-q tile: waves 0-3 process kv[0,1024),
// waves 4-7 kv[1024,2048) — identical 16q/wave pipelines in separate LDS
// double-buffers. Static-max softmax is exactly additive across halves.
// Merge (fp32, round-13 fix): after the loop K/V LDS is dead, so half 1
// spills O in fp32 into the Ks region (stride 68 floats -> 2-way max bank
// aliasing) and l into Vs; one barrier; half 0 merges in fp32 and writes
// vals. No extra LDS (65.5KB), no bf16 rounding of half-1's O (round 12's
// absmax 0.073 -> back to the fp32-merge level).
// Swapped QK keeps P lane-local (q=li); P->PV-B-frag via cvt_pk +
// permlane32/16 transposes (reg0 word as vdst). XCD-pinned block map.
__global__ __launch_bounds__(512) void attn_kernel(
    const bf16* __restrict__ QK, const bf16* __restrict__ Vt,
    bf16* __restrict__ vals)
{
  __shared__ bf16 Ks[2][2][64][64];   // [half][buf][row][col]; dead after loop
  __shared__ bf16 Vs[2][2][64][64];   // V^T tiles: [d][kv];   dead after loop
  int tid=threadIdx.x, w=tid>>6, la=tid&63;
  int half = w>>2, wl = w&3;
  int id = blockIdx.x;
  int xcd = id & 7, idx = id >> 3;       // 768 = 8 * 96, bijective
  int bh  = xcd*3 + idx/32;              // 3 (b,h) per XCD -> K/V L2-resident
  int qt  = idx & 31;
  int b = bh/NH, hh = bh%NH;
  int g=la>>4, li=la&15;
  int lr=la>>3;
  int lx=li&7;
  int lcs=((la&7)^lr)*8;           // swizzled source column (elements)
  size_t qrow0=(size_t)b*SEQ + qt*64;
  int kv0 = half*1024;

  // Q frags (B-operand: Q[q=li][k]), pre-scaled by LOG2E in GEMM1; registers
  bf16x8 qf[2];
  {
    const bf16* qp = QK + (qrow0 + wl*16 + li)*1536 + hh*64;
    qf[0] = *(const bf16x8*)(qp + g*8);
    qf[1] = *(const bf16x8*)(qp + 32 + g*8);
  }

  const bf16* Kbase = QK + (size_t)b*SEQ*1536 + 768 + hh*64;
  const bf16* Vbase = Vt + (size_t)(b*NH+hh)*HD*SEQ;

  auto stage = [&](int tt, int bbuf) {
    int j0 = kv0 + tt*64;
    #pragma unroll
    for (int i=0;i<2;i++){ int c=i*4+wl;
      gload16(Kbase + (size_t)(j0 + c*8 + lr)*1536 + lcs, &Ks[half][bbuf][c*8][0]);
      gload16(Vbase + (size_t)(c*8 + lr)*SEQ + j0 + lcs,  &Vs[half][bbuf][c*8][0]); }
  };

  stage(0,0);
  asm volatile("s_waitcnt vmcnt(0)" ::: "memory");
  __builtin_amdgcn_s_barrier();
  __builtin_amdgcn_sched_barrier(0);

  f32x4 o[4] = {};
  float lp[4] = {0.f,0.f,0.f,0.f};

  for (int t=0;t<16;t++){
    int bb = t&1;
    if (t+1 < 16) stage(t+1, bb^1);
    // S = K Q^T (swapped): lane holds S[kv=nf*16+g*4+r][q=li]
    f32x4 s[4] = {};
    #pragma unroll
    for (int kk=0;kk<2;kk++){
      bf16x8 kf[4];
      #pragma unroll
      for (int nf=0;nf<4;nf++){
        int row = nf*16+li;
        kf[nf] = *(const bf16x8*)((const char*)&Ks[half][bb][0][0] + row*128 + (((kk*4+g)^lx)<<4));
      }
      __builtin_amdgcn_s_setprio(1);
      #pragma unroll
      for (int nf=0;nf<4;nf++)
        s[nf] = __builtin_amdgcn_mfma_f32_16x16x32_bf16(kf[nf], qf[kk], s[nf], 0,0,0);
      __builtin_amdgcn_s_setprio(0);
    }
    // static-max softmax: p = 2^s, lane-local (q = li)
    float p[4][4];
    #pragma unroll
    for (int nf=0;nf<4;nf++){
      #pragma unroll
      for (int r=0;r<4;r++){
        p[nf][r] = __builtin_amdgcn_exp2f(s[nf][r]);
        lp[nf] += p[nf][r];
      }
    }
    // in-register exchange: PV B-frags pa[ks] = P[kv][q=li]
    bf16x8 pa[2];
    #pragma unroll
    for (int ks=0;ks<2;ks++){
      unsigned int c00,c01,c10,c11;
      asm("v_cvt_pk_bf16_f32 %0, %1, %2" : "=v"(c00) : "v"(p[2*ks  ][0]), "v"(p[2*ks  ][1]));
      asm("v_cvt_pk_bf16_f32 %0, %1, %2" : "=v"(c01) : "v"(p[2*ks  ][2]), "v"(p[2*ks  ][3]));
      asm("v_cvt_pk_bf16_f32 %0, %1, %2" : "=v"(c10) : "v"(p[2*ks+1][0]), "v"(p[2*ks+1][1]));
      asm("v_cvt_pk_bf16_f32 %0, %1, %2" : "=v"(c11) : "v"(p[2*ks+1][2]), "v"(p[2*ks+1][3]));
      // transpose (reg-bit, lane-b5) then (reg-bit, lane-b4); reg0 word = vdst
      asm("v_permlane32_swap_b32 %0, %1" : "+v"(c00), "+v"(c10));
      asm("v_permlane32_swap_b32 %0, %1" : "+v"(c01), "+v"(c11));
      asm("v_permlane16_swap_b32 %0, %1" : "+v"(c00), "+v"(c10));
      asm("v_permlane16_swap_b32 %0, %1" : "+v"(c01), "+v"(c11));
      u32x4v cc = {c00, c01, c10, c11};
      pa[ks] = __builtin_bit_cast(bf16x8, cc);
    }
    // PV: O[d][q] += V^T[d][kv] * P[kv][q]
    #pragma unroll
    for (int ks=0;ks<2;ks++){
      bf16x8 vb[4];
      #pragma unroll
      for (int df=0;df<4;df++){
        int row = df*16+li;
        vb[df] = *(const bf16x8*)((const char*)&Vs[half][bb][0][0] + row*128 + (((ks*4+g)^lx)<<4));
      }
      __builtin_amdgcn_s_setprio(1);
      #pragma unroll
      for (int df=0;df<4;df++)
        o[df] = __builtin_amdgcn_mfma_f32_16x16x32_bf16(vb[df], pa[ks], o[df], 0,0,0);
      __builtin_amdgcn_s_setprio(0);
    }
    if (t+1 < 16) {
      asm volatile("s_waitcnt vmcnt(0)" ::: "memory");
      __builtin_amdgcn_s_barrier();
      __builtin_amdgcn_sched_barrier(0);
    }
  }
  // merge halves in fp32 through the now-dead K/V LDS.
  // lane holds O[d=df*16+g*4+r][q=li]; lsum = full row sum for q=li.
  float lsum = lp[0]+lp[1]+lp[2]+lp[3];
  lsum += __shfl_xor(lsum, 16, 64);
  lsum += __shfl_xor(lsum, 32, 64);
  __syncthreads();                          // all waves done with Ks/Vs
  float* om  = (float*)&Ks[0][0][0][0];     // [4 waves][16 q][68 pad] fp32
  float* lmf = (float*)&Vs[0][0][0][0];     // [64] fp32
  if (half==1){
    float* orow = om + (wl*16+li)*68;
    #pragma unroll
    for (int df=0;df<4;df++)
      *reinterpret_cast<f32x4*>(orow + df*16 + g*4) = o[df];
    if (g==0) lmf[wl*16+li] = lsum;
  }
  __syncthreads();
  if (half==0){
    const float* orow = om + (wl*16+li)*68;
    float ltot = lsum + lmf[wl*16+li];
    float fac = ATT_SCALE / ltot;
    bf16* vrow = vals + (qrow0 + wl*16 + li)*DM + hh*64;
    #pragma unroll
    for (int df=0;df<4;df++){
      f32x4 pv = *reinterpret_cast<const f32x4*>(orow + df*16 + g*4);
      u16x4 u;
      #pragma unroll
      for (int r=0;r<4;r++){
        bf16 bv = (bf16)((o[df][r] + pv[r]) * fac);
        u[r] = __builtin_bit_cast(unsigned short, bv);
      }
      *reinterpret_cast<u16x4*>(vrow + df*16 + g*4) = u;
    }
  }
}

// ---------------- launch -----------------------------------------------------
extern "C" void kernel_launch(void* const* d_in, const int* in_sizes, int n_in,
                              void* d_out, int out_size, void* d_ws, size_t ws_size,
                              hipStream_t stream)
{
  const float* x     = (const float*)d_in[0];
  const float* Wq    = (const float*)d_in[1];
  const float* Wk    = (const float*)d_in[2];
  const float* Wv    = (const float*)d_in[3];
  const float* Wo    = (const float*)d_in[4];
  const float* bo    = (const float*)d_in[5];
  const float* gamma = (const float*)d_in[6];
  const float* beta  = (const float*)d_in[7];
  float* out = (float*)d_out;
  char* ws = (char*)d_ws;

  bf16* h     = (bf16*)(ws + 0);          // 4096*768*2    = 6291456
  bf16* vals  = (bf16*)(ws + 0);          // alias of h (h dead after GEMM1)
  bf16* Wqkvt = (bf16*)(ws + 6291456);    // 2304*768*2    = 3538944
  bf16* Wot   = (bf16*)(ws + 9830400);    // 768*768*2     = 1179648
  bf16* QKb   = (bf16*)(ws + 11010048);   // 4096*1536*2   = 12582912
  bf16* Vt    = (bf16*)(ws + 23592960);   // 24*64*2048*2  = 6291456
  (void)ws_size; (void)in_sizes; (void)n_in; (void)out_size;

  prep_kernel<<<dim3(6400), dim3(256), 0, stream>>>(
      x, gamma, beta, h, Wq, Wk, Wv, Wo, Wqkvt, Wot);
  gemm_bt<128,128,32,2,2,0><<<dim3(18,32), dim3(256), 0, stream>>>(
      h, Wqkvt, DM, QKb, Vt, nullptr, nullptr, nullptr);
  attn_kernel<<<dim3(768), dim3(512), 0, stream>>>(QKb, Vt, vals);
  gemm_bt<64,64,64,2,2,1><<<dim3(12,64), dim3(256), 0, stream>>>(
      vals, Wot, DM, nullptr, nullptr, out, bo, x);
}

// Round 14
// 100.069 us; speedup vs baseline: 1.1605x; 1.0257x over previous
//
#include <hip/hip_runtime.h>
#include <stdint.h>

typedef __bf16 bf16;
typedef __bf16 bf16x8 __attribute__((ext_vector_type(8)));
typedef float  f32x4  __attribute__((ext_vector_type(4)));
typedef unsigned short u16x4 __attribute__((ext_vector_type(4)));
typedef unsigned int   u32x4v __attribute__((ext_vector_type(4)));

#define SEQ   2048
#define DM    768
#define NH    12
#define HD    64
#define ATT_SCALE 0.125f
#define LOG2E 1.44269504f
#define LN_EPS 1e-5f

// async global->LDS, 16B per lane; LDS dest is wave-uniform base + lane*16
__device__ __forceinline__ void gload16(const void* g, void* l) {
  __builtin_amdgcn_global_load_lds((const __attribute__((address_space(1))) void*)g,
                                   (__attribute__((address_space(3))) void*)l,
                                   16, 0, 0);
}

// ---------------- prep: LN (blocks 0..4095) + weight transpose (4096..6399) -
__global__ __launch_bounds__(256) void prep_kernel(
    const float* __restrict__ x, const float* __restrict__ gamma,
    const float* __restrict__ beta, bf16* __restrict__ h,
    const float* __restrict__ Wq, const float* __restrict__ Wk,
    const float* __restrict__ Wv, const float* __restrict__ Wo,
    bf16* __restrict__ Wqkvt, bf16* __restrict__ Wot)
{
  __shared__ float smem[32*33];
  int bid = blockIdx.x, t = threadIdx.x;
  if (bid < 4096) {
    const float* xr = x + (size_t)bid*DM;
    float v0 = xr[t], v1 = xr[t+256], v2 = xr[t+512];
    float s = v0+v1+v2;
    float q = v0*v0+v1*v1+v2*v2;
    #pragma unroll
    for (int m=32;m>=1;m>>=1){ s += __shfl_xor(s,m,64); q += __shfl_xor(q,m,64); }
    float* rs = smem; float* rq = smem+8;
    int w = t>>6;
    if ((t&63)==0){ rs[w]=s; rq[w]=q; }
    __syncthreads();
    float S = rs[0]+rs[1]+rs[2]+rs[3];
    float Q = rq[0]+rq[1]+rq[2]+rq[3];
    float mean = S*(1.0f/DM);
    float var  = Q*(1.0f/DM) - mean*mean;
    float rstd = rsqrtf(var + LN_EPS);
    bf16* hr = h + (size_t)bid*DM;
    hr[t]     = (bf16)((v0-mean)*rstd*gamma[t]     + beta[t]);
    hr[t+256] = (bf16)((v1-mean)*rstd*gamma[t+256] + beta[t+256]);
    hr[t+512] = (bf16)((v2-mean)*rstd*gamma[t+512] + beta[t+512]);
  } else {
    int tb = bid - 4096;
    int z = tb/576, rem = tb%576;
    int r0 = (rem/24)*32, c0 = (rem%24)*32;
    int tx = t&31, ty = t>>5;   // (32,8)
    float (*tile)[33] = (float(*)[33])smem;
    const float* src = (z==0)?Wq:(z==1)?Wk:(z==2)?Wv:Wo;
    #pragma unroll
    for (int i=ty;i<32;i+=8) tile[i][tx] = src[(size_t)(r0+i)*DM + c0+tx];
    __syncthreads();
    bf16* dst = (z<3) ? (Wqkvt + (size_t)z*DM*DM) : Wot;
    #pragma unroll
    for (int i=ty;i<32;i+=8) dst[(size_t)(c0+i)*DM + r0+tx] = (bf16)tile[tx][i];
  }
}

// ---------------- GEMM: C = A * Bt^T, templated BK, 3-buffer counted vmcnt --
// EPI 0: QKV epilogue (Q cols scaled LOG2E; V -> V^T [b][h][d][n])
// EPI 1: out fp32 = acc + bo[col] + x[row][col]
template<int BM, int BN, int BK, int WM, int WN, int EPI>
__global__ __launch_bounds__(256) void gemm_bt(
    const bf16* __restrict__ A, const bf16* __restrict__ Bt, int K,
    bf16* __restrict__ qk, bf16* __restrict__ vt,
    float* __restrict__ out, const float* __restrict__ bo, const float* __restrict__ xres)
{
  constexpr int MF  = BM/(WM*16);
  constexpr int NF  = BN/(WN*16);
  constexpr int GL  = (BM+BN)*BK/2048;  // gloads per wave per stage
  constexpr int RPI = 512/BK;           // rows covered per gload16 wave-instr
  constexpr int KKN = BK/32;            // MFMA k-steps per tile
  __shared__ bf16 As[3][BM][BK];
  __shared__ bf16 Bs[3][BN][BK];
  int tid = threadIdx.x, w = tid>>6, la = tid&63;
  int bn = blockIdx.x, bm = blockIdx.y;
  int wm = w / WN, wn = w % WN;
  int g = la>>4, li = la&15;
  int sr = la / (BK/8);                 // staging row within group
  int sc = (la % (BK/8))*8;             // staging col (elements)
  f32x4 acc[MF][NF] = {};
  const int KT = K/BK;

  auto stage = [&](int kt, int bb) {
    int k0 = kt*BK;
    #pragma unroll
    for (int i=0;i<BM/(RPI*4);i++){ int r0 = (i*4+w)*RPI;
      gload16(A + ((size_t)(bm*BM + r0 + sr))*K + k0 + sc, &As[bb][r0][0]); }
    #pragma unroll
    for (int i=0;i<BN/(RPI*4);i++){ int r0 = (i*4+w)*RPI;
      gload16(Bt + ((size_t)(bn*BN + r0 + sr))*K + k0 + sc, &Bs[bb][r0][0]); }
  };

  stage(0,0); stage(1,1);
  asm volatile("s_waitcnt vmcnt(%0)" :: "n"(GL) : "memory");
  __builtin_amdgcn_s_barrier();
  __builtin_amdgcn_sched_barrier(0);

  for (int kt=0; kt<KT; ++kt) {
    int bb = kt%3;
    if (kt+2 < KT) stage(kt+2, (kt+2)%3);
    #pragma unroll
    for (int kk=0;kk<KKN;kk++){
      bf16x8 af[MF], bfr[NF];
      #pragma unroll
      for (int i=0;i<MF;i++) af[i]  = *(const bf16x8*)&As[bb][wm*(BM/WM)+i*16+li][kk*32+g*8];
      #pragma unroll
      for (int j=0;j<NF;j++) bfr[j] = *(const bf16x8*)&Bs[bb][wn*(BN/WN)+j*16+li][kk*32+g*8];
      __builtin_amdgcn_s_setprio(1);
      #pragma unroll
      for (int i=0;i<MF;i++)
        #pragma unroll
        for (int j=0;j<NF;j++)
          acc[i][j] = __builtin_amdgcn_mfma_f32_16x16x32_bf16(af[i], bfr[j], acc[i][j], 0,0,0);
      __builtin_amdgcn_s_setprio(0);
    }
    if (kt+1 < KT) {
      if (kt+2 < KT) asm volatile("s_waitcnt vmcnt(%0)" :: "n"(GL) : "memory");
      else           asm volatile("s_waitcnt vmcnt(0)" ::: "memory");
      __builtin_amdgcn_s_barrier();
      __builtin_amdgcn_sched_barrier(0);
    }
  }

  #pragma unroll
  for (int i=0;i<MF;i++){
    int row0 = bm*BM + wm*(BM/WM) + i*16 + g*4;
    #pragma unroll
    for (int j=0;j<NF;j++){
      int col = bn*BN + wn*(BN/WN) + j*16 + li;
      if (EPI==0){
        if (col < 1536) {
          float qs = (col < 768) ? LOG2E : 1.0f;   // uniform per j-tile (768%BN==0)
          #pragma unroll
          for (int r=0;r<4;r++) qk[(size_t)(row0+r)*1536 + col] = (bf16)(acc[i][j][r]*qs);
        } else {
          int cv = col - 1536; int hh = cv>>6, dd = cv&63;
          int b_ = row0>>11,  n0 = row0&2047;
          u16x4 u;
          #pragma unroll
          for (int r=0;r<4;r++){ bf16 bv = (bf16)acc[i][j][r];
            u[r] = __builtin_bit_cast(unsigned short, bv); }
          *reinterpret_cast<u16x4*>(vt + ((size_t)((b_*NH+hh)*HD+dd))*SEQ + n0) = u;
        }
      } else {
        float bb2 = bo[col];
        #pragma unroll
        for (int r=0;r<4;r++){ size_t idx = (size_t)(row0+r)*DM + col;
          out[idx] = acc[i][j][r] + bb2 + xres[idx]; }
      }
    }
  }
}

// ---------------- flash attention: 512 thr, in-block KV-split, 32q/wave -----
// Rounds 7-13 synthesis: every config pins the LDS pipe at ~75% busy; R10's
// 32q read-halving was cancelled by halved residency. This config gets BOTH:
// 8 waves (0-3: kv[0,1024), 4-7: kv[1024,2048)), each wave 32 q-rows (two
// 16q subtiles qh) -> block = 128-q tile. Grid 24bh x 16qt = 384 blocks,
// ALL resident (<=2 blocks/CU) -> wall ~= one block duration, no 2nd
// scheduling round. Device-wide LDS reads halve vs R13 (16 frag reads/iter
// now serve 2048 scores). VGPR <128 (no ones-MFMA; VALU lp chains).
// Merge in fp32 through the dead K/V LDS (om stride 64 fp32, f32x4 slot
// XOR-swizzled by row&15 -> ~2-way max bank aliasing); static-max softmax
// is exactly additive across halves. Swapped QK keeps P lane-local (q=li);
// P->PV-B-frag via cvt_pk + permlane32/16 transposes (reg0 word as vdst).
__global__ __launch_bounds__(512) void attn_kernel(
    const bf16* __restrict__ QK, const bf16* __restrict__ Vt,
    bf16* __restrict__ vals)
{
  __shared__ bf16 Ks[2][2][64][64];   // [half][buf][row][col]; dead after loop
  __shared__ bf16 Vs[2][2][64][64];   // V^T tiles: [d][kv];   dead after loop
  int tid=threadIdx.x, w=tid>>6, la=tid&63;
  int half = w>>2, wl = w&3;
  int id = blockIdx.x;
  int xcd = id & 7, idx = id >> 3;       // 384 = 8 * 48, bijective
  int bh  = xcd*3 + idx/16;              // 3 (b,h) per XCD -> K/V L2-resident
  int qt  = idx & 15;                    // 128-q tiles
  int b = bh/NH, hh = bh%NH;
  int g=la>>4, li=la&15;
  int lr=la>>3;
  int lx=li&7;
  int lcs=((la&7)^lr)*8;           // swizzled source column (elements)
  size_t qrow0=(size_t)b*SEQ + qt*128;
  int kv0 = half*1024;

  // Q frags (B-operand: Q[q][k]) for two q-subtiles, pre-scaled by LOG2E
  bf16x8 qf[2][2];   // [kk][qh]
  #pragma unroll
  for (int qh=0;qh<2;qh++){
    const bf16* qp = QK + (qrow0 + wl*32 + qh*16 + li)*1536 + hh*64;
    qf[0][qh] = *(const bf16x8*)(qp + g*8);
    qf[1][qh] = *(const bf16x8*)(qp + 32 + g*8);
  }

  const bf16* Kbase = QK + (size_t)b*SEQ*1536 + 768 + hh*64;
  const bf16* Vbase = Vt + (size_t)(b*NH+hh)*HD*SEQ;

  // 4 waves per half stage 8 row-groups: wave wl does groups {wl, 4+wl} -> GL=4
  auto stage = [&](int tt, int bbuf) {
    int j0 = kv0 + tt*64;
    #pragma unroll
    for (int i=0;i<2;i++){ int c=i*4+wl;
      gload16(Kbase + (size_t)(j0 + c*8 + lr)*1536 + lcs, &Ks[half][bbuf][c*8][0]);
      gload16(Vbase + (size_t)(c*8 + lr)*SEQ + j0 + lcs,  &Vs[half][bbuf][c*8][0]); }
  };

  stage(0,0);
  asm volatile("s_waitcnt vmcnt(0)" ::: "memory");
  __builtin_amdgcn_s_barrier();
  __builtin_amdgcn_sched_barrier(0);

  f32x4 o[2][4] = {};        // [qh][df]
  float lp[2][2] = {};       // [qh][chain]

  for (int t=0;t<16;t++){
    int bb = t&1;
    if (t+1 < 16) stage(t+1, bb^1);
    // S = K Q^T (swapped): lane holds S[kv=nf*16+g*4+r][q=li] per q-subtile
    f32x4 s[2][4] = {};
    #pragma unroll
    for (int kk=0;kk<2;kk++){
      bf16x8 kf[4];
      #pragma unroll
      for (int nf=0;nf<4;nf++){
        int row = nf*16+li;
        kf[nf] = *(const bf16x8*)((const char*)&Ks[half][bb][0][0] + row*128 + (((kk*4+g)^lx)<<4));
      }
      __builtin_amdgcn_s_setprio(1);
      #pragma unroll
      for (int nf=0;nf<4;nf++){
        s[0][nf] = __builtin_amdgcn_mfma_f32_16x16x32_bf16(kf[nf], qf[kk][0], s[0][nf], 0,0,0);
        s[1][nf] = __builtin_amdgcn_mfma_f32_16x16x32_bf16(kf[nf], qf[kk][1], s[1][nf], 0,0,0);
      }
      __builtin_amdgcn_s_setprio(0);
    }
    // static-max softmax + in-register exchange, per q-subtile
    bf16x8 pa[2][2];   // [qh][ks]
    #pragma unroll
    for (int qh=0;qh<2;qh++){
      float p[4][4];
      #pragma unroll
      for (int nf=0;nf<4;nf++)
        #pragma unroll
        for (int r=0;r<4;r++){
          p[nf][r] = __builtin_amdgcn_exp2f(s[qh][nf][r]);
          lp[qh][nf&1] += p[nf][r];
        }
      #pragma unroll
      for (int ks=0;ks<2;ks++){
        unsigned int c00,c01,c10,c11;
        asm("v_cvt_pk_bf16_f32 %0, %1, %2" : "=v"(c00) : "v"(p[2*ks  ][0]), "v"(p[2*ks  ][1]));
        asm("v_cvt_pk_bf16_f32 %0, %1, %2" : "=v"(c01) : "v"(p[2*ks  ][2]), "v"(p[2*ks  ][3]));
        asm("v_cvt_pk_bf16_f32 %0, %1, %2" : "=v"(c10) : "v"(p[2*ks+1][0]), "v"(p[2*ks+1][1]));
        asm("v_cvt_pk_bf16_f32 %0, %1, %2" : "=v"(c11) : "v"(p[2*ks+1][2]), "v"(p[2*ks+1][3]));
        // transpose (reg-bit, lane-b5) then (reg-bit, lane-b4); reg0 word = vdst
        asm("v_permlane32_swap_b32 %0, %1" : "+v"(c00), "+v"(c10));
        asm("v_permlane32_swap_b32 %0, %1" : "+v"(c01), "+v"(c11));
        asm("v_permlane16_swap_b32 %0, %1" : "+v"(c00), "+v"(c10));
        asm("v_permlane16_swap_b32 %0, %1" : "+v"(c01), "+v"(c11));
        u32x4v cc = {c00, c01, c10, c11};
        pa[qh][ks] = __builtin_bit_cast(bf16x8, cc);
      }
    }
    // PV: O[d][q] += V^T[d][kv] * P[kv][q] — 8 vb reads serve 16 MFMAs
    #pragma unroll
    for (int ks=0;ks<2;ks++){
      bf16x8 vb[4];
      #pragma unroll
      for (int df=0;df<4;df++){
        int row = df*16+li;
        vb[df] = *(const bf16x8*)((const char*)&Vs[half][bb][0][0] + row*128 + (((ks*4+g)^lx)<<4));
      }
      __builtin_amdgcn_s_setprio(1);
      #pragma unroll
      for (int qh=0;qh<2;qh++)
        #pragma unroll
        for (int df=0;df<4;df++)
          o[qh][df] = __builtin_amdgcn_mfma_f32_16x16x32_bf16(vb[df], pa[qh][ks], o[qh][df], 0,0,0);
      __builtin_amdgcn_s_setprio(0);
    }
    if (t+1 < 16) {
      asm volatile("s_waitcnt vmcnt(0)" ::: "memory");
      __builtin_amdgcn_s_barrier();
      __builtin_amdgcn_sched_barrier(0);
    }
  }
  // merge halves in fp32 through the now-dead K/V LDS.
  // lane holds O[d=df*16+g*4+r][q=li]; lsum[qh] = full row sum for that q.
  float lsum[2];
  #pragma unroll
  for (int qh=0;qh<2;qh++){
    float v = lp[qh][0] + lp[qh][1];
    v += __shfl_xor(v, 16, 64);
    v += __shfl_xor(v, 32, 64);
    lsum[qh] = v;
  }
  __syncthreads();                          // all waves done with Ks/Vs
  float* om  = (float*)&Ks[0][0][0][0];     // [128 q][64 d] fp32, slot-swizzled
  float* lmf = (float*)&Vs[0][0][0][0];     // [128] fp32
  if (half==1){
    #pragma unroll
    for (int qh=0;qh<2;qh++){
      int row = wl*32 + qh*16 + li;
      float* orow = om + row*64;
      #pragma unroll
      for (int df=0;df<4;df++){
        int slot = (df*4 + g) ^ (row & 15);
        *reinterpret_cast<f32x4*>(orow + slot*4) = o[qh][df];
      }
      if (g==0) lmf[row] = lsum[qh];
    }
  }
  __syncthreads();
  if (half==0){
    #pragma unroll
    for (int qh=0;qh<2;qh++){
      int row = wl*32 + qh*16 + li;
      const float* orow = om + row*64;
      float ltot = lsum[qh] + lmf[row];
      float fac = ATT_SCALE / ltot;
      bf16* vrow = vals + (qrow0 + row)*DM + hh*64;
      #pragma unroll
      for (int df=0;df<4;df++){
        int slot = (df*4 + g) ^ (row & 15);
        f32x4 pv = *reinterpret_cast<const f32x4*>(orow + slot*4);
        u16x4 u;
        #pragma unroll
        for (int r=0;r<4;r++){
          bf16 bv = (bf16)((o[qh][df][r] + pv[r]) * fac);
          u[r] = __builtin_bit_cast(unsigned short, bv);
        }
        *reinterpret_cast<u16x4*>(vrow + df*16 + g*4) = u;
      }
    }
  }
}

// ---------------- launch -----------------------------------------------------
extern "C" void kernel_launch(void* const* d_in, const int* in_sizes, int n_in,
                              void* d_out, int out_size, void* d_ws, size_t ws_size,
                              hipStream_t stream)
{
  const float* x     = (const float*)d_in[0];
  const float* Wq    = (const float*)d_in[1];
  const float* Wk    = (const float*)d_in[2];
  const float* Wv    = (const float*)d_in[3];
  const float* Wo    = (const float*)d_in[4];
  const float* bo    = (const float*)d_in[5];
  const float* gamma = (const float*)d_in[6];
  const float* beta  = (const float*)d_in[7];
  float* out = (float*)d_out;
  char* ws = (char*)d_ws;

  bf16* h     = (bf16*)(ws + 0);          // 4096*768*2    = 6291456
  bf16* vals  = (bf16*)(ws + 0);          // alias of h (h dead after GEMM1)
  bf16* Wqkvt = (bf16*)(ws + 6291456);    // 2304*768*2    = 3538944
  bf16* Wot   = (bf16*)(ws + 9830400);    // 768*768*2     = 1179648
  bf16* QKb   = (bf16*)(ws + 11010048);   // 4096*1536*2   = 12582912
  bf16* Vt    = (bf16*)(ws + 23592960);   // 24*64*2048*2  = 6291456
  (void)ws_size; (void)in_sizes; (void)n_in; (void)out_size;

  prep_kernel<<<dim3(6400), dim3(256), 0, stream>>>(
      x, gamma, beta, h, Wq, Wk, Wv, Wo, Wqkvt, Wot);
  gemm_bt<128,128,32,2,2,0><<<dim3(18,32), dim3(256), 0, stream>>>(
      h, Wqkvt, DM, QKb, Vt, nullptr, nullptr, nullptr);
  attn_kernel<<<dim3(384), dim3(512), 0, stream>>>(QKb, Vt, vals);
  gemm_bt<64,64,64,2,2,1><<<dim3(12,64), dim3(256), 0, stream>>>(
      vals, Wot, DM, nullptr, nullptr, out, bo, x);
}

// Round 15
// 99.751 us; speedup vs baseline: 1.1642x; 1.0032x over previous
//
#include <hip/hip_runtime.h>
#include <stdint.h>

typedef __bf16 bf16;
typedef __bf16 bf16x8 __attribute__((ext_vector_type(8)));
typedef float  f32x4  __attribute__((ext_vector_type(4)));
typedef unsigned short u16x4 __attribute__((ext_vector_type(4)));
typedef unsigned int   u32x4v __attribute__((ext_vector_type(4)));

#define SEQ   2048
#define DM    768
#define NH    12
#define HD    64
#define ATT_SCALE 0.125f
#define LOG2E 1.44269504f
#define LN_EPS 1e-5f

// async global->LDS, 16B per lane; LDS dest is wave-uniform base + lane*16
__device__ __forceinline__ void gload16(const void* g, void* l) {
  __builtin_amdgcn_global_load_lds((const __attribute__((address_space(1))) void*)g,
                                   (__attribute__((address_space(3))) void*)l,
                                   16, 0, 0);
}

// ---------------- prep: LN (blocks 0..4095) + weight transpose (4096..6399) -
__global__ __launch_bounds__(256) void prep_kernel(
    const float* __restrict__ x, const float* __restrict__ gamma,
    const float* __restrict__ beta, bf16* __restrict__ h,
    const float* __restrict__ Wq, const float* __restrict__ Wk,
    const float* __restrict__ Wv, const float* __restrict__ Wo,
    bf16* __restrict__ Wqkvt, bf16* __restrict__ Wot)
{
  __shared__ float smem[32*33];
  int bid = blockIdx.x, t = threadIdx.x;
  if (bid < 4096) {
    const float* xr = x + (size_t)bid*DM;
    float v0 = xr[t], v1 = xr[t+256], v2 = xr[t+512];
    float s = v0+v1+v2;
    float q = v0*v0+v1*v1+v2*v2;
    #pragma unroll
    for (int m=32;m>=1;m>>=1){ s += __shfl_xor(s,m,64); q += __shfl_xor(q,m,64); }
    float* rs = smem; float* rq = smem+8;
    int w = t>>6;
    if ((t&63)==0){ rs[w]=s; rq[w]=q; }
    __syncthreads();
    float S = rs[0]+rs[1]+rs[2]+rs[3];
    float Q = rq[0]+rq[1]+rq[2]+rq[3];
    float mean = S*(1.0f/DM);
    float var  = Q*(1.0f/DM) - mean*mean;
    float rstd = rsqrtf(var + LN_EPS);
    bf16* hr = h + (size_t)bid*DM;
    hr[t]     = (bf16)((v0-mean)*rstd*gamma[t]     + beta[t]);
    hr[t+256] = (bf16)((v1-mean)*rstd*gamma[t+256] + beta[t+256]);
    hr[t+512] = (bf16)((v2-mean)*rstd*gamma[t+512] + beta[t+512]);
  } else {
    int tb = bid - 4096;
    int z = tb/576, rem = tb%576;
    int r0 = (rem/24)*32, c0 = (rem%24)*32;
    int tx = t&31, ty = t>>5;   // (32,8)
    float (*tile)[33] = (float(*)[33])smem;
    const float* src = (z==0)?Wq:(z==1)?Wk:(z==2)?Wv:Wo;
    #pragma unroll
    for (int i=ty;i<32;i+=8) tile[i][tx] = src[(size_t)(r0+i)*DM + c0+tx];
    __syncthreads();
    bf16* dst = (z<3) ? (Wqkvt + (size_t)z*DM*DM) : Wot;
    #pragma unroll
    for (int i=ty;i<32;i+=8) dst[(size_t)(c0+i)*DM + r0+tx] = (bf16)tile[tx][i];
  }
}

// ---------------- GEMM: C = A * Bt^T, templated BK, 3-buffer counted vmcnt --
// EPI 0: QKV epilogue (Q cols scaled LOG2E; V -> V^T [b][h][d][n])
// EPI 1: out fp32 = acc + bo[col] + x[row][col]
template<int BM, int BN, int BK, int WM, int WN, int EPI>
__global__ __launch_bounds__(256) void gemm_bt(
    const bf16* __restrict__ A, const bf16* __restrict__ Bt, int K,
    bf16* __restrict__ qk, bf16* __restrict__ vt,
    float* __restrict__ out, const float* __restrict__ bo, const float* __restrict__ xres)
{
  constexpr int MF  = BM/(WM*16);
  constexpr int NF  = BN/(WN*16);
  constexpr int GL  = (BM+BN)*BK/2048;  // gloads per wave per stage
  constexpr int RPI = 512/BK;           // rows covered per gload16 wave-instr
  constexpr int KKN = BK/32;            // MFMA k-steps per tile
  __shared__ bf16 As[3][BM][BK];
  __shared__ bf16 Bs[3][BN][BK];
  int tid = threadIdx.x, w = tid>>6, la = tid&63;
  int bn = blockIdx.x, bm = blockIdx.y;
  int wm = w / WN, wn = w % WN;
  int g = la>>4, li = la&15;
  int sr = la / (BK/8);                 // staging row within group
  int sc = (la % (BK/8))*8;             // staging col (elements)
  f32x4 acc[MF][NF] = {};
  const int KT = K/BK;

  auto stage = [&](int kt, int bb) {
    int k0 = kt*BK;
    #pragma unroll
    for (int i=0;i<BM/(RPI*4);i++){ int r0 = (i*4+w)*RPI;
      gload16(A + ((size_t)(bm*BM + r0 + sr))*K + k0 + sc, &As[bb][r0][0]); }
    #pragma unroll
    for (int i=0;i<BN/(RPI*4);i++){ int r0 = (i*4+w)*RPI;
      gload16(Bt + ((size_t)(bn*BN + r0 + sr))*K + k0 + sc, &Bs[bb][r0][0]); }
  };

  stage(0,0); stage(1,1);
  asm volatile("s_waitcnt vmcnt(%0)" :: "n"(GL) : "memory");
  __builtin_amdgcn_s_barrier();
  __builtin_amdgcn_sched_barrier(0);

  for (int kt=0; kt<KT; ++kt) {
    int bb = kt%3;
    if (kt+2 < KT) stage(kt+2, (kt+2)%3);
    #pragma unroll
    for (int kk=0;kk<KKN;kk++){
      bf16x8 af[MF], bfr[NF];
      #pragma unroll
      for (int i=0;i<MF;i++) af[i]  = *(const bf16x8*)&As[bb][wm*(BM/WM)+i*16+li][kk*32+g*8];
      #pragma unroll
      for (int j=0;j<NF;j++) bfr[j] = *(const bf16x8*)&Bs[bb][wn*(BN/WN)+j*16+li][kk*32+g*8];
      __builtin_amdgcn_s_setprio(1);
      #pragma unroll
      for (int i=0;i<MF;i++)
        #pragma unroll
        for (int j=0;j<NF;j++)
          acc[i][j] = __builtin_amdgcn_mfma_f32_16x16x32_bf16(af[i], bfr[j], acc[i][j], 0,0,0);
      __builtin_amdgcn_s_setprio(0);
    }
    if (kt+1 < KT) {
      if (kt+2 < KT) asm volatile("s_waitcnt vmcnt(%0)" :: "n"(GL) : "memory");
      else           asm volatile("s_waitcnt vmcnt(0)" ::: "memory");
      __builtin_amdgcn_s_barrier();
      __builtin_amdgcn_sched_barrier(0);
    }
  }

  #pragma unroll
  for (int i=0;i<MF;i++){
    int row0 = bm*BM + wm*(BM/WM) + i*16 + g*4;
    #pragma unroll
    for (int j=0;j<NF;j++){
      int col = bn*BN + wn*(BN/WN) + j*16 + li;
      if (EPI==0){
        if (col < 1536) {
          float qs = (col < 768) ? LOG2E : 1.0f;   // uniform per j-tile (768%BN==0)
          #pragma unroll
          for (int r=0;r<4;r++) qk[(size_t)(row0+r)*1536 + col] = (bf16)(acc[i][j][r]*qs);
        } else {
          int cv = col - 1536; int hh = cv>>6, dd = cv&63;
          int b_ = row0>>11,  n0 = row0&2047;
          u16x4 u;
          #pragma unroll
          for (int r=0;r<4;r++){ bf16 bv = (bf16)acc[i][j][r];
            u[r] = __builtin_bit_cast(unsigned short, bv); }
          *reinterpret_cast<u16x4*>(vt + ((size_t)((b_*NH+hh)*HD+dd))*SEQ + n0) = u;
        }
      } else {
        float bb2 = bo[col];
        #pragma unroll
        for (int r=0;r<4;r++){ size_t idx = (size_t)(row0+r)*DM + col;
          out[idx] = acc[i][j][r] + bb2 + xres[idx]; }
      }
    }
  }
}

// ---------------- flash attention: balanced 64q blocks, 32q/wave, kv-split --
// R14 post-mortem: grid 384 = 1.5 blocks/CU -> half the CUs ran 2 blocks,
// half ran 1; wall = 2T vs balanced 1.5T. This round re-packs R14's EXACT
// per-wave structure (32q/wave, KVBLK=64, kv-split) into 256-thr blocks:
// waves 0-1 = kv[0,1024), waves 2-3 = kv[1024,2048), each wave 32q of the
// same 64-q tile. Grid = 24bh x 32qt = 768 = EXACTLY 3 blocks/CU (XCD-pinned
// 96/XCD = 3/CU), 12 waves/CU uniform. To fit 3 blocks in LDS: K is
// SINGLE-buffered (read first in the iter; restaged right after barrier_A
// which follows QK), V double-buffered. 48.3KB -> 3 x 48.3 = 145KB < 160KB.
// Iter: QK -> [barA; stage K(t+1),V(t+1)] -> softmax -> PV -> [vmcnt(0); barB]
// (stage latency hidden under softmax+PV; vmcnt-before-barrier publishes all
// waves' loads). fp32 merge through dead K-region LDS (om slot-swizzled).
// Swapped QK keeps P lane-local; P->PV-B via cvt_pk+permlane (reg0 as vdst).
__global__ __launch_bounds__(256) void attn_kernel(
    const bf16* __restrict__ QK, const bf16* __restrict__ Vt,
    bf16* __restrict__ vals)
{
  // manual layout: [0,16384) K tiles (half*8192), dead after loop -> om fp32
  //                [16384,49152) V tiles ((half*2+buf)*8192)
  //                [49152,49408) lmf (half-1 partial l, 64 f32)
  __shared__ char smem[49408];
  int tid=threadIdx.x, w=tid>>6, la=tid&63;
  int half = w>>1, wl = w&1;
  int id = blockIdx.x;
  int xcd = id & 7, idx = id >> 3;       // 768 = 8 * 96, bijective
  int bh  = xcd*3 + idx/32;              // 3 (b,h) per XCD -> K/V L2-resident
  int qt  = idx & 31;                    // 64-q tiles
  int b = bh/NH, hh = bh%NH;
  int g=la>>4, li=la&15;
  int lr=la>>3;
  int lx=li&7;
  int lcs=((la&7)^lr)*8;           // swizzled source column (elements)
  size_t qrow0=(size_t)b*SEQ + qt*64;
  int kv0 = half*1024;

  // Q frags (B-operand: Q[q][k]) for two 16-q subtiles, pre-scaled by LOG2E
  bf16x8 qf[2][2];   // [kk][qh]
  #pragma unroll
  for (int qh=0;qh<2;qh++){
    const bf16* qp = QK + (qrow0 + wl*32 + qh*16 + li)*1536 + hh*64;
    qf[0][qh] = *(const bf16x8*)(qp + g*8);
    qf[1][qh] = *(const bf16x8*)(qp + 32 + g*8);
  }

  const bf16* Kbase = QK + (size_t)b*SEQ*1536 + 768 + hh*64;
  const bf16* Vbase = Vt + (size_t)(b*NH+hh)*HD*SEQ;
  char* kreg = smem + half*8192;

  // per wave: K tile rows [wl*32, wl*32+32), 4 gloads; V^T same rows, 4 gloads
  auto stageK = [&](int tt) {
    int j0 = kv0 + tt*64;
    #pragma unroll
    for (int i=0;i<4;i++){ int r0 = wl*32 + i*8;
      gload16(Kbase + (size_t)(j0 + r0 + lr)*1536 + lcs, kreg + r0*128); }
  };
  auto stageV = [&](int tt, int vb) {
    int j0 = kv0 + tt*64;
    char* vreg = smem + 16384 + (half*2+vb)*8192;
    #pragma unroll
    for (int i=0;i<4;i++){ int r0 = wl*32 + i*8;
      gload16(Vbase + (size_t)(r0 + lr)*SEQ + j0 + lcs, vreg + r0*128); }
  };

  stageK(0); stageV(0,0);
  asm volatile("s_waitcnt vmcnt(0)" ::: "memory");
  __builtin_amdgcn_s_barrier();
  __builtin_amdgcn_sched_barrier(0);

  f32x4 o[2][4] = {};        // [qh][df]
  float lp[2][2] = {};       // [qh][chain]

  for (int t=0;t<16;t++){
    // S = K Q^T (swapped): lane holds S[kv=nf*16+g*4+r][q=li] per q-subtile
    f32x4 s[2][4] = {};
    #pragma unroll
    for (int kk=0;kk<2;kk++){
      bf16x8 kf[4];
      #pragma unroll
      for (int nf=0;nf<4;nf++){
        int row = nf*16+li;
        kf[nf] = *(const bf16x8*)(kreg + row*128 + (((kk*4+g)^lx)<<4));
      }
      __builtin_amdgcn_s_setprio(1);
      #pragma unroll
      for (int nf=0;nf<4;nf++){
        s[0][nf] = __builtin_amdgcn_mfma_f32_16x16x32_bf16(kf[nf], qf[kk][0], s[0][nf], 0,0,0);
        s[1][nf] = __builtin_amdgcn_mfma_f32_16x16x32_bf16(kf[nf], qf[kk][1], s[1][nf], 0,0,0);
      }
      __builtin_amdgcn_s_setprio(0);
    }
    // K readers done -> restage K (and next V) under softmax+PV cover
    if (t+1 < 16) {
      __builtin_amdgcn_s_barrier();
      stageK(t+1);
      stageV(t+1, (t+1)&1);
    }
    // static-max softmax + in-register exchange, per q-subtile
    bf16x8 pa[2][2];   // [qh][ks]
    #pragma unroll
    for (int qh=0;qh<2;qh++){
      float p[4][4];
      #pragma unroll
      for (int nf=0;nf<4;nf++)
        #pragma unroll
        for (int r=0;r<4;r++){
          p[nf][r] = __builtin_amdgcn_exp2f(s[qh][nf][r]);
          lp[qh][nf&1] += p[nf][r];
        }
      #pragma unroll
      for (int ks=0;ks<2;ks++){
        unsigned int c00,c01,c10,c11;
        asm("v_cvt_pk_bf16_f32 %0, %1, %2" : "=v"(c00) : "v"(p[2*ks  ][0]), "v"(p[2*ks  ][1]));
        asm("v_cvt_pk_bf16_f32 %0, %1, %2" : "=v"(c01) : "v"(p[2*ks  ][2]), "v"(p[2*ks  ][3]));
        asm("v_cvt_pk_bf16_f32 %0, %1, %2" : "=v"(c10) : "v"(p[2*ks+1][0]), "v"(p[2*ks+1][1]));
        asm("v_cvt_pk_bf16_f32 %0, %1, %2" : "=v"(c11) : "v"(p[2*ks+1][2]), "v"(p[2*ks+1][3]));
        // transpose (reg-bit, lane-b5) then (reg-bit, lane-b4); reg0 word = vdst
        asm("v_permlane32_swap_b32 %0, %1" : "+v"(c00), "+v"(c10));
        asm("v_permlane32_swap_b32 %0, %1" : "+v"(c01), "+v"(c11));
        asm("v_permlane16_swap_b32 %0, %1" : "+v"(c00), "+v"(c10));
        asm("v_permlane16_swap_b32 %0, %1" : "+v"(c01), "+v"(c11));
        u32x4v cc = {c00, c01, c10, c11};
        pa[qh][ks] = __builtin_bit_cast(bf16x8, cc);
      }
    }
    // PV: O[d][q] += V^T[d][kv] * P[kv][q] — 8 vb reads serve 16 MFMAs
    const char* vreg = smem + 16384 + (half*2+(t&1))*8192;
    #pragma unroll
    for (int ks=0;ks<2;ks++){
      bf16x8 vb[4];
      #pragma unroll
      for (int df=0;df<4;df++){
        int row = df*16+li;
        vb[df] = *(const bf16x8*)(vreg + row*128 + (((ks*4+g)^lx)<<4));
      }
      __builtin_amdgcn_s_setprio(1);
      #pragma unroll
      for (int qh=0;qh<2;qh++)
        #pragma unroll
        for (int df=0;df<4;df++)
          o[qh][df] = __builtin_amdgcn_mfma_f32_16x16x32_bf16(vb[df], pa[qh][ks], o[qh][df], 0,0,0);
      __builtin_amdgcn_s_setprio(0);
    }
    if (t+1 < 16) {
      asm volatile("s_waitcnt vmcnt(0)" ::: "memory");   // own stages drained
      __builtin_amdgcn_s_barrier();                       // publish to block
      __builtin_amdgcn_sched_barrier(0);
    }
  }
  // merge halves in fp32 through the now-dead K-region LDS.
  // lane holds O[d=df*16+g*4+r][q=li]; lsum[qh] = full row sum for that q.
  float lsum[2];
  #pragma unroll
  for (int qh=0;qh<2;qh++){
    float v = lp[qh][0] + lp[qh][1];
    v += __shfl_xor(v, 16, 64);
    v += __shfl_xor(v, 32, 64);
    lsum[qh] = v;
  }
  __syncthreads();                          // all waves done with K/V LDS
  float* om  = (float*)smem;                // [64 q][64 d] fp32, slot-swizzled
  float* lmf = (float*)(smem + 49152);      // [64] fp32
  if (half==1){
    #pragma unroll
    for (int qh=0;qh<2;qh++){
      int row = wl*32 + qh*16 + li;
      float* orow = om + row*64;
      #pragma unroll
      for (int df=0;df<4;df++){
        int slot = (df*4 + g) ^ (row & 15);
        *reinterpret_cast<f32x4*>(orow + slot*4) = o[qh][df];
      }
      if (g==0) lmf[row] = lsum[qh];
    }
  }
  __syncthreads();
  if (half==0){
    #pragma unroll
    for (int qh=0;qh<2;qh++){
      int row = wl*32 + qh*16 + li;
      const float* orow = om + row*64;
      float ltot = lsum[qh] + lmf[row];
      float fac = ATT_SCALE / ltot;
      bf16* vrow = vals + (qrow0 + row)*DM + hh*64;
      #pragma unroll
      for (int df=0;df<4;df++){
        int slot = (df*4 + g) ^ (row & 15);
        f32x4 pv = *reinterpret_cast<const f32x4*>(orow + slot*4);
        u16x4 u;
        #pragma unroll
        for (int r=0;r<4;r++){
          bf16 bv = (bf16)((o[qh][df][r] + pv[r]) * fac);
          u[r] = __builtin_bit_cast(unsigned short, bv);
        }
        *reinterpret_cast<u16x4*>(vrow + df*16 + g*4) = u;
      }
    }
  }
}

// ---------------- launch -----------------------------------------------------
extern "C" void kernel_launch(void* const* d_in, const int* in_sizes, int n_in,
                              void* d_out, int out_size, void* d_ws, size_t ws_size,
                              hipStream_t stream)
{
  const float* x     = (const float*)d_in[0];
  const float* Wq    = (const float*)d_in[1];
  const float* Wk    = (const float*)d_in[2];
  const float* Wv    = (const float*)d_in[3];
  const float* Wo    = (const float*)d_in[4];
  const float* bo    = (const float*)d_in[5];
  const float* gamma = (const float*)d_in[6];
  const float* beta  = (const float*)d_in[7];
  float* out = (float*)d_out;
  char* ws = (char*)d_ws;

  bf16* h     = (bf16*)(ws + 0);          // 4096*768*2    = 6291456
  bf16* vals  = (bf16*)(ws + 0);          // alias of h (h dead after GEMM1)
  bf16* Wqkvt = (bf16*)(ws + 6291456);    // 2304*768*2    = 3538944
  bf16* Wot   = (bf16*)(ws + 9830400);    // 768*768*2     = 1179648
  bf16* QKb   = (bf16*)(ws + 11010048);   // 4096*1536*2   = 12582912
  bf16* Vt    = (bf16*)(ws + 23592960);   // 24*64*2048*2  = 6291456
  (void)ws_size; (void)in_sizes; (void)n_in; (void)out_size;

  prep_kernel<<<dim3(6400), dim3(256), 0, stream>>>(
      x, gamma, beta, h, Wq, Wk, Wv, Wo, Wqkvt, Wot);
  gemm_bt<128,128,32,2,2,0><<<dim3(18,32), dim3(256), 0, stream>>>(
      h, Wqkvt, DM, QKb, Vt, nullptr, nullptr, nullptr);
  attn_kernel<<<dim3(768), dim3(256), 0, stream>>>(QKb, Vt, vals);
  gemm_bt<64,64,64,2,2,1><<<dim3(12,64), dim3(256), 0, stream>>>(
      vals, Wot, DM, nullptr, nullptr, out, bo, x);
}

// Round 16
// 95.848 us; speedup vs baseline: 1.2117x; 1.0407x over previous
//
#include <hip/hip_runtime.h>
#include <stdint.h>

typedef __bf16 bf16;
typedef __bf16 bf16x8 __attribute__((ext_vector_type(8)));
typedef float  f32x4  __attribute__((ext_vector_type(4)));
typedef unsigned short u16x4 __attribute__((ext_vector_type(4)));
typedef unsigned int   u32x4v __attribute__((ext_vector_type(4)));

#define SEQ   2048
#define DM    768
#define NH    12
#define HD    64
#define ATT_SCALE 0.125f
#define LOG2E 1.44269504f
#define LN_EPS 1e-5f

// async global->LDS, 16B per lane; LDS dest is wave-uniform base + lane*16
__device__ __forceinline__ void gload16(const void* g, void* l) {
  __builtin_amdgcn_global_load_lds((const __attribute__((address_space(1))) void*)g,
                                   (__attribute__((address_space(3))) void*)l,
                                   16, 0, 0);
}

// ---------------- prep: LN (blocks 0..4095) + weight transpose (4096..6399) -
__global__ __launch_bounds__(256) void prep_kernel(
    const float* __restrict__ x, const float* __restrict__ gamma,
    const float* __restrict__ beta, bf16* __restrict__ h,
    const float* __restrict__ Wq, const float* __restrict__ Wk,
    const float* __restrict__ Wv, const float* __restrict__ Wo,
    bf16* __restrict__ Wqkvt, bf16* __restrict__ Wot)
{
  __shared__ float smem[32*33];
  int bid = blockIdx.x, t = threadIdx.x;
  if (bid < 4096) {
    const float* xr = x + (size_t)bid*DM;
    float v0 = xr[t], v1 = xr[t+256], v2 = xr[t+512];
    float s = v0+v1+v2;
    float q = v0*v0+v1*v1+v2*v2;
    #pragma unroll
    for (int m=32;m>=1;m>>=1){ s += __shfl_xor(s,m,64); q += __shfl_xor(q,m,64); }
    float* rs = smem; float* rq = smem+8;
    int w = t>>6;
    if ((t&63)==0){ rs[w]=s; rq[w]=q; }
    __syncthreads();
    float S = rs[0]+rs[1]+rs[2]+rs[3];
    float Q = rq[0]+rq[1]+rq[2]+rq[3];
    float mean = S*(1.0f/DM);
    float var  = Q*(1.0f/DM) - mean*mean;
    float rstd = rsqrtf(var + LN_EPS);
    bf16* hr = h + (size_t)bid*DM;
    hr[t]     = (bf16)((v0-mean)*rstd*gamma[t]     + beta[t]);
    hr[t+256] = (bf16)((v1-mean)*rstd*gamma[t+256] + beta[t+256]);
    hr[t+512] = (bf16)((v2-mean)*rstd*gamma[t+512] + beta[t+512]);
  } else {
    int tb = bid - 4096;
    int z = tb/576, rem = tb%576;
    int r0 = (rem/24)*32, c0 = (rem%24)*32;
    int tx = t&31, ty = t>>5;   // (32,8)
    float (*tile)[33] = (float(*)[33])smem;
    const float* src = (z==0)?Wq:(z==1)?Wk:(z==2)?Wv:Wo;
    #pragma unroll
    for (int i=ty;i<32;i+=8) tile[i][tx] = src[(size_t)(r0+i)*DM + c0+tx];
    __syncthreads();
    bf16* dst = (z<3) ? (Wqkvt + (size_t)z*DM*DM) : Wot;
    #pragma unroll
    for (int i=ty;i<32;i+=8) dst[(size_t)(c0+i)*DM + r0+tx] = (bf16)tile[tx][i];
  }
}

// ---------------- GEMM: C = A * Bt^T, templated BK + waves, 3-buffer pipeline
// LDS XOR-swizzled (round 16): staging pre-swizzles the SOURCE slot by
// row&SMASK (dest stays linear per global_load_lds rules), frag reads XOR the
// slot back. BK=64: 8 slots -> conflict-free; BK=32: 4 slots -> 8-way
// conflict reduced to 4-way (geometric floor).
// EPI 0: QKV epilogue (Q cols scaled LOG2E; V -> V^T [b][h][d][n])
// EPI 1: out fp32 = acc + bo[col] + x[row][col]
template<int BM, int BN, int BK, int WM, int WN, int EPI>
__global__ __launch_bounds__(WM*WN*64) void gemm_bt(
    const bf16* __restrict__ A, const bf16* __restrict__ Bt, int K,
    bf16* __restrict__ qk, bf16* __restrict__ vt,
    float* __restrict__ out, const float* __restrict__ bo, const float* __restrict__ xres)
{
  constexpr int NW    = WM*WN;            // waves per block
  constexpr int MF    = BM/(WM*16);
  constexpr int NF    = BN/(WN*16);
  constexpr int GL    = (BM+BN)*BK/(512*NW); // gloads per wave per stage
  constexpr int RPI   = 512/BK;           // rows covered per gload16 instr
  constexpr int KKN   = BK/32;            // MFMA k-steps per tile
  constexpr int SLOTS = BK/8;             // 16B slots per row
  constexpr int SMASK = SLOTS-1;
  __shared__ bf16 As[3][BM][BK];
  __shared__ bf16 Bs[3][BN][BK];
  int tid = threadIdx.x, w = tid>>6, la = tid&63;
  int bn = blockIdx.x, bm = blockIdx.y;
  int wm = w / WN, wn = w % WN;
  int g = la>>4, li = la&15;
  int sr = la / SLOTS;                    // staging row within group
  int sc = ((la % SLOTS) ^ (sr & SMASK))*8; // pre-swizzled source col (elems)
  f32x4 acc[MF][NF] = {};
  const int KT = K/BK;

  auto stage = [&](int kt, int bb) {
    int k0 = kt*BK;
    #pragma unroll
    for (int i=0;i<BM/(RPI*NW);i++){ int r0 = (i*NW+w)*RPI;
      gload16(A + ((size_t)(bm*BM + r0 + sr))*K + k0 + sc, &As[bb][r0][0]); }
    #pragma unroll
    for (int i=0;i<BN/(RPI*NW);i++){ int r0 = (i*NW+w)*RPI;
      gload16(Bt + ((size_t)(bn*BN + r0 + sr))*K + k0 + sc, &Bs[bb][r0][0]); }
  };

  stage(0,0); stage(1,1);
  asm volatile("s_waitcnt vmcnt(%0)" :: "n"(GL) : "memory");
  __builtin_amdgcn_s_barrier();
  __builtin_amdgcn_sched_barrier(0);

  const char* abase = (const char*)&As[0][0][0];
  const char* bbase = (const char*)&Bs[0][0][0];
  for (int kt=0; kt<KT; ++kt) {
    int bb = kt%3;
    if (kt+2 < KT) stage(kt+2, (kt+2)%3);
    #pragma unroll
    for (int kk=0;kk<KKN;kk++){
      bf16x8 af[MF], bfr[NF];
      #pragma unroll
      for (int i=0;i<MF;i++){
        int row = wm*(BM/WM)+i*16+li;
        int slot = (kk*4+g) ^ (li & SMASK);
        af[i] = *(const bf16x8*)(abase + (size_t)bb*BM*BK*2 + row*BK*2 + slot*16);
      }
      #pragma unroll
      for (int j=0;j<NF;j++){
        int row = wn*(BN/WN)+j*16+li;
        int slot = (kk*4+g) ^ (li & SMASK);
        bfr[j] = *(const bf16x8*)(bbase + (size_t)bb*BN*BK*2 + row*BK*2 + slot*16);
      }
      __builtin_amdgcn_s_setprio(1);
      #pragma unroll
      for (int i=0;i<MF;i++)
        #pragma unroll
        for (int j=0;j<NF;j++)
          acc[i][j] = __builtin_amdgcn_mfma_f32_16x16x32_bf16(af[i], bfr[j], acc[i][j], 0,0,0);
      __builtin_amdgcn_s_setprio(0);
    }
    if (kt+1 < KT) {
      if (kt+2 < KT) asm volatile("s_waitcnt vmcnt(%0)" :: "n"(GL) : "memory");
      else           asm volatile("s_waitcnt vmcnt(0)" ::: "memory");
      __builtin_amdgcn_s_barrier();
      __builtin_amdgcn_sched_barrier(0);
    }
  }

  #pragma unroll
  for (int i=0;i<MF;i++){
    int row0 = bm*BM + wm*(BM/WM) + i*16 + g*4;
    #pragma unroll
    for (int j=0;j<NF;j++){
      int col = bn*BN + wn*(BN/WN) + j*16 + li;
      if (EPI==0){
        if (col < 1536) {
          float qs = (col < 768) ? LOG2E : 1.0f;   // uniform per j-tile (768%BN==0)
          #pragma unroll
          for (int r=0;r<4;r++) qk[(size_t)(row0+r)*1536 + col] = (bf16)(acc[i][j][r]*qs);
        } else {
          int cv = col - 1536; int hh = cv>>6, dd = cv&63;
          int b_ = row0>>11,  n0 = row0&2047;
          u16x4 u;
          #pragma unroll
          for (int r=0;r<4;r++){ bf16 bv = (bf16)acc[i][j][r];
            u[r] = __builtin_bit_cast(unsigned short, bv); }
          *reinterpret_cast<u16x4*>(vt + ((size_t)((b_*NH+hh)*HD+dd))*SEQ + n0) = u;
        }
      } else {
        float bb2 = bo[col];
        #pragma unroll
        for (int r=0;r<4;r++){ size_t idx = (size_t)(row0+r)*DM + col;
          out[idx] = acc[i][j][r] + bb2 + xres[idx]; }
      }
    }
  }
}

// ---------------- flash attention: FROZEN at round-15 form (control) --------
// 256-thr blocks, waves 0-1 kv[0,1024) / 2-3 kv[1024,2048), 32q/wave,
// K single-buffered + V double-buffered, fp32 merge through dead K LDS.
__global__ __launch_bounds__(256) void attn_kernel(
    const bf16* __restrict__ QK, const bf16* __restrict__ Vt,
    bf16* __restrict__ vals)
{
  __shared__ char smem[49408];
  int tid=threadIdx.x, w=tid>>6, la=tid&63;
  int half = w>>1, wl = w&1;
  int id = blockIdx.x;
  int xcd = id & 7, idx = id >> 3;       // 768 = 8 * 96, bijective
  int bh  = xcd*3 + idx/32;              // 3 (b,h) per XCD -> K/V L2-resident
  int qt  = idx & 31;                    // 64-q tiles
  int b = bh/NH, hh = bh%NH;
  int g=la>>4, li=la&15;
  int lr=la>>3;
  int lx=li&7;
  int lcs=((la&7)^lr)*8;           // swizzled source column (elements)
  size_t qrow0=(size_t)b*SEQ + qt*64;
  int kv0 = half*1024;

  bf16x8 qf[2][2];   // [kk][qh]
  #pragma unroll
  for (int qh=0;qh<2;qh++){
    const bf16* qp = QK + (qrow0 + wl*32 + qh*16 + li)*1536 + hh*64;
    qf[0][qh] = *(const bf16x8*)(qp + g*8);
    qf[1][qh] = *(const bf16x8*)(qp + 32 + g*8);
  }

  const bf16* Kbase = QK + (size_t)b*SEQ*1536 + 768 + hh*64;
  const bf16* Vbase = Vt + (size_t)(b*NH+hh)*HD*SEQ;
  char* kreg = smem + half*8192;

  auto stageK = [&](int tt) {
    int j0 = kv0 + tt*64;
    #pragma unroll
    for (int i=0;i<4;i++){ int r0 = wl*32 + i*8;
      gload16(Kbase + (size_t)(j0 + r0 + lr)*1536 + lcs, kreg + r0*128); }
  };
  auto stageV = [&](int tt, int vb) {
    int j0 = kv0 + tt*64;
    char* vreg = smem + 16384 + (half*2+vb)*8192;
    #pragma unroll
    for (int i=0;i<4;i++){ int r0 = wl*32 + i*8;
      gload16(Vbase + (size_t)(r0 + lr)*SEQ + j0 + lcs, vreg + r0*128); }
  };

  stageK(0); stageV(0,0);
  asm volatile("s_waitcnt vmcnt(0)" ::: "memory");
  __builtin_amdgcn_s_barrier();
  __builtin_amdgcn_sched_barrier(0);

  f32x4 o[2][4] = {};        // [qh][df]
  float lp[2][2] = {};       // [qh][chain]

  for (int t=0;t<16;t++){
    f32x4 s[2][4] = {};
    #pragma unroll
    for (int kk=0;kk<2;kk++){
      bf16x8 kf[4];
      #pragma unroll
      for (int nf=0;nf<4;nf++){
        int row = nf*16+li;
        kf[nf] = *(const bf16x8*)(kreg + row*128 + (((kk*4+g)^lx)<<4));
      }
      __builtin_amdgcn_s_setprio(1);
      #pragma unroll
      for (int nf=0;nf<4;nf++){
        s[0][nf] = __builtin_amdgcn_mfma_f32_16x16x32_bf16(kf[nf], qf[kk][0], s[0][nf], 0,0,0);
        s[1][nf] = __builtin_amdgcn_mfma_f32_16x16x32_bf16(kf[nf], qf[kk][1], s[1][nf], 0,0,0);
      }
      __builtin_amdgcn_s_setprio(0);
    }
    if (t+1 < 16) {
      __builtin_amdgcn_s_barrier();
      stageK(t+1);
      stageV(t+1, (t+1)&1);
    }
    bf16x8 pa[2][2];   // [qh][ks]
    #pragma unroll
    for (int qh=0;qh<2;qh++){
      float p[4][4];
      #pragma unroll
      for (int nf=0;nf<4;nf++)
        #pragma unroll
        for (int r=0;r<4;r++){
          p[nf][r] = __builtin_amdgcn_exp2f(s[qh][nf][r]);
          lp[qh][nf&1] += p[nf][r];
        }
      #pragma unroll
      for (int ks=0;ks<2;ks++){
        unsigned int c00,c01,c10,c11;
        asm("v_cvt_pk_bf16_f32 %0, %1, %2" : "=v"(c00) : "v"(p[2*ks  ][0]), "v"(p[2*ks  ][1]));
        asm("v_cvt_pk_bf16_f32 %0, %1, %2" : "=v"(c01) : "v"(p[2*ks  ][2]), "v"(p[2*ks  ][3]));
        asm("v_cvt_pk_bf16_f32 %0, %1, %2" : "=v"(c10) : "v"(p[2*ks+1][0]), "v"(p[2*ks+1][1]));
        asm("v_cvt_pk_bf16_f32 %0, %1, %2" : "=v"(c11) : "v"(p[2*ks+1][2]), "v"(p[2*ks+1][3]));
        asm("v_permlane32_swap_b32 %0, %1" : "+v"(c00), "+v"(c10));
        asm("v_permlane32_swap_b32 %0, %1" : "+v"(c01), "+v"(c11));
        asm("v_permlane16_swap_b32 %0, %1" : "+v"(c00), "+v"(c10));
        asm("v_permlane16_swap_b32 %0, %1" : "+v"(c01), "+v"(c11));
        u32x4v cc = {c00, c01, c10, c11};
        pa[qh][ks] = __builtin_bit_cast(bf16x8, cc);
      }
    }
    const char* vreg = smem + 16384 + (half*2+(t&1))*8192;
    #pragma unroll
    for (int ks=0;ks<2;ks++){
      bf16x8 vb[4];
      #pragma unroll
      for (int df=0;df<4;df++){
        int row = df*16+li;
        vb[df] = *(const bf16x8*)(vreg + row*128 + (((ks*4+g)^lx)<<4));
      }
      __builtin_amdgcn_s_setprio(1);
      #pragma unroll
      for (int qh=0;qh<2;qh++)
        #pragma unroll
        for (int df=0;df<4;df++)
          o[qh][df] = __builtin_amdgcn_mfma_f32_16x16x32_bf16(vb[df], pa[qh][ks], o[qh][df], 0,0,0);
      __builtin_amdgcn_s_setprio(0);
    }
    if (t+1 < 16) {
      asm volatile("s_waitcnt vmcnt(0)" ::: "memory");
      __builtin_amdgcn_s_barrier();
      __builtin_amdgcn_sched_barrier(0);
    }
  }
  float lsum[2];
  #pragma unroll
  for (int qh=0;qh<2;qh++){
    float v = lp[qh][0] + lp[qh][1];
    v += __shfl_xor(v, 16, 64);
    v += __shfl_xor(v, 32, 64);
    lsum[qh] = v;
  }
  __syncthreads();
  float* om  = (float*)smem;                // [64 q][64 d] fp32, slot-swizzled
  float* lmf = (float*)(smem + 49152);      // [64] fp32
  if (half==1){
    #pragma unroll
    for (int qh=0;qh<2;qh++){
      int row = wl*32 + qh*16 + li;
      float* orow = om + row*64;
      #pragma unroll
      for (int df=0;df<4;df++){
        int slot = (df*4 + g) ^ (row & 15);
        *reinterpret_cast<f32x4*>(orow + slot*4) = o[qh][df];
      }
      if (g==0) lmf[row] = lsum[qh];
    }
  }
  __syncthreads();
  if (half==0){
    #pragma unroll
    for (int qh=0;qh<2;qh++){
      int row = wl*32 + qh*16 + li;
      const float* orow = om + row*64;
      float ltot = lsum[qh] + lmf[row];
      float fac = ATT_SCALE / ltot;
      bf16* vrow = vals + (qrow0 + row)*DM + hh*64;
      #pragma unroll
      for (int df=0;df<4;df++){
        int slot = (df*4 + g) ^ (row & 15);
        f32x4 pv = *reinterpret_cast<const f32x4*>(orow + slot*4);
        u16x4 u;
        #pragma unroll
        for (int r=0;r<4;r++){
          bf16 bv = (bf16)((o[qh][df][r] + pv[r]) * fac);
          u[r] = __builtin_bit_cast(unsigned short, bv);
        }
        *reinterpret_cast<u16x4*>(vrow + df*16 + g*4) = u;
      }
    }
  }
}

// ---------------- launch -----------------------------------------------------
extern "C" void kernel_launch(void* const* d_in, const int* in_sizes, int n_in,
                              void* d_out, int out_size, void* d_ws, size_t ws_size,
                              hipStream_t stream)
{
  const float* x     = (const float*)d_in[0];
  const float* Wq    = (const float*)d_in[1];
  const float* Wk    = (const float*)d_in[2];
  const float* Wv    = (const float*)d_in[3];
  const float* Wo    = (const float*)d_in[4];
  const float* bo    = (const float*)d_in[5];
  const float* gamma = (const float*)d_in[6];
  const float* beta  = (const float*)d_in[7];
  float* out = (float*)d_out;
  char* ws = (char*)d_ws;

  bf16* h     = (bf16*)(ws + 0);          // 4096*768*2    = 6291456
  bf16* vals  = (bf16*)(ws + 0);          // alias of h (h dead after GEMM1)
  bf16* Wqkvt = (bf16*)(ws + 6291456);    // 2304*768*2    = 3538944
  bf16* Wot   = (bf16*)(ws + 9830400);    // 768*768*2     = 1179648
  bf16* QKb   = (bf16*)(ws + 11010048);   // 4096*1536*2   = 12582912
  bf16* Vt    = (bf16*)(ws + 23592960);   // 24*64*2048*2  = 6291456
  (void)ws_size; (void)in_sizes; (void)n_in; (void)out_size;

  prep_kernel<<<dim3(6400), dim3(256), 0, stream>>>(
      x, gamma, beta, h, Wq, Wk, Wv, Wo, Wqkvt, Wot);
  gemm_bt<128,128,32,2,4,0><<<dim3(18,32), dim3(512), 0, stream>>>(
      h, Wqkvt, DM, QKb, Vt, nullptr, nullptr, nullptr);
  attn_kernel<<<dim3(768), dim3(256), 0, stream>>>(QKb, Vt, vals);
  gemm_bt<64,64,64,2,2,1><<<dim3(12,64), dim3(256), 0, stream>>>(
      vals, Wot, DM, nullptr, nullptr, out, bo, x);
}